// Round 7
// baseline (2005.336 us; speedup 1.0000x reference)
//
#include <hip/hip_runtime.h>

#define BB 4
#define NN 8192
#define CC 64
#define SS 2048
#define KK 32
#define MROWS (BB*SS*KK)   // 262144

typedef __attribute__((ext_vector_type(8))) short bf16x8_t;
typedef __attribute__((ext_vector_type(4))) float f32x4_t;
typedef __attribute__((ext_vector_type(2))) float f32x2_t;

__device__ __forceinline__ float bf2f(unsigned short u){
  union { unsigned int i; float f; } v; v.i = ((unsigned int)u) << 16; return v.f;
}
__device__ __forceinline__ unsigned short f2bf(float f){
  union { float f; unsigned int i; } v; v.f = f;
  unsigned int u = v.i;
  unsigned int r = (u + 0x7FFFu + ((u >> 16) & 1u)) >> 16;
  return (unsigned short)r;
}
__device__ __forceinline__ float i2f(int i){ union { int i; float f; } v; v.i = i; return v.f; }
__device__ __forceinline__ int f2i(float f){ union { float f; int i; } v; v.f = f; return v.i; }

// ---------------- dtype detection ----------------
__global__ void detect_kernel(const void* pts, int* flag){
  __shared__ int cnt;
  if (threadIdx.x == 0) cnt = 0;
  __syncthreads();
  unsigned short u = ((const unsigned short*)pts)[threadIdx.x];
  int e = (u >> 7) & 0xFF;
  if (e != 0 && (e < 112 || e > 143)) atomicAdd(&cnt, 1);
  __syncthreads();
  if (threadIdx.x == 0) *flag = (cnt > 32) ? 1 : 0;
}

// ---------------- merged prep: transpose + converts + weight packs + stats zero ----------------
__device__ __forceinline__ void pack_dev(const void* src, unsigned short* dst,
    int CTS, int KSTEPS, int IN, int remap, int idx, bool isf){
  int total = CTS*KSTEPS*512;
  if (idx >= total) return;
  int f = idx >> 9, lane = (idx >> 3) & 63, j = idx & 7;
  int ct = f / KSTEPS, ks = f % KSTEPS;
  int n = ct*16 + (lane & 15);
  int k = ks*32 + (lane >> 4)*8 + j;
  int ksrc;
  if (remap){ ksrc = (k < 64) ? (k + 3) : (k < 67 ? k - 64 : -1); }
  else      { ksrc = (k < IN) ? k : -1; }
  float v = 0.f;
  if (ksrc >= 0){
    size_t si = (size_t)n*IN + ksrc;
    v = isf ? ((const float*)src)[si] : bf2f(((const unsigned short*)src)[si]);
  }
  dst[idx] = f2bf(v);
}

__global__ __launch_bounds__(256) void prep_kernel(
    const void* xyz_in, const void* pts_in,
    const void* w0_in, const void* w1_in, const void* w2_in,
    const void* g0, const void* b0, const void* g1, const void* b1,
    const void* g2, const void* b2,
    float* xyzf, unsigned short* ptsb,
    unsigned short* w0p, unsigned short* w1p, unsigned short* w2p,
    float* gbf, float* stats, const int* flag)
{
  __shared__ float tile[64][65];
  int blk = blockIdx.x, tid = threadIdx.x;
  bool isf = (*flag != 0);
  if (blk < 512){
    int b = blk >> 7, n0 = (blk & 127) * 64;
    #pragma unroll
    for (int k = 0; k < 16; k++){
      int idx = k*256 + tid; int c = idx >> 6; int ni = idx & 63;
      size_t src = ((size_t)b*CC + c)*NN + n0 + ni;
      tile[c][ni] = isf ? ((const float*)pts_in)[src] : bf2f(((const unsigned short*)pts_in)[src]);
    }
    __syncthreads();
    #pragma unroll
    for (int k = 0; k < 16; k++){
      int idx = k*256 + tid; int ni = idx >> 6; int c = idx & 63;
      ptsb[((size_t)b*NN + n0 + ni)*CC + c] = f2bf(tile[c][ni]);
    }
  } else if (blk < 896){
    int i = (blk - 512)*256 + tid;
    if (i < BB*NN*3)
      xyzf[i] = isf ? ((const float*)xyz_in)[i] : bf2f(((const unsigned short*)xyz_in)[i]);
  } else if (blk < 900){
    int i = (blk - 896)*256 + tid;
    if (i < 896){
      const void* src; int off;
      if      (i < 64)  { src = g0; off = i; }
      else if (i < 128) { src = b0; off = i - 64; }
      else if (i < 256) { src = g1; off = i - 128; }
      else if (i < 384) { src = b1; off = i - 256; }
      else if (i < 640) { src = g2; off = i - 384; }
      else              { src = b2; off = i - 640; }
      gbf[i] = isf ? ((const float*)src)[off] : bf2f(((const unsigned short*)src)[off]);
      stats[i] = 0.f;
    }
  } else if (blk < 924){
    pack_dev(w0_in, w0p, 4, 3, 67, 1, (blk-900)*256 + tid, isf);
  } else if (blk < 956){
    pack_dev(w1_in, w1p, 8, 2, 64, 0, (blk-924)*256 + tid, isf);
  } else {
    pack_dev(w2_in, w2p, 16, 4, 128, 0, (blk-956)*256 + tid, isf);
  }
}

// ---------------- Morton 13-bit counting sort (one block per batch) ----------------
__device__ __forceinline__ unsigned mspread(unsigned v){
  v = (v | (v << 16)) & 0x030000FFu;
  v = (v | (v <<  8)) & 0x0300F00Fu;
  v = (v | (v <<  4)) & 0x030C30C3u;
  v = (v | (v <<  2)) & 0x09249249u;
  return v;
}
__global__ __launch_bounds__(1024) void morton_sort(const float* xyzf,
    float* psx, float* psy, float* psz, int* iorig){
  int b = blockIdx.x, tid = threadIdx.x;
  int lane = tid & 63, wid = tid >> 6;
  const float* xb = xyzf + (size_t)b*NN*3;
  __shared__ unsigned curs[NN];     // 32 KiB: histogram, then exclusive-prefix cursors
  __shared__ float rbb[96];
  __shared__ unsigned wsum[16];
  float x[8], y[8], z[8];
  {
    const float4* p4 = (const float4*)(xb + (size_t)tid*24);
    float4 A=p4[0],B2=p4[1],C=p4[2],D=p4[3],E=p4[4],F=p4[5];
    x[0]=A.x;  y[0]=A.y;  z[0]=A.z;
    x[1]=A.w;  y[1]=B2.x; z[1]=B2.y;
    x[2]=B2.z; y[2]=B2.w; z[2]=C.x;
    x[3]=C.y;  y[3]=C.z;  z[3]=C.w;
    x[4]=D.x;  y[4]=D.y;  z[4]=D.z;
    x[5]=D.w;  y[5]=E.x;  z[5]=E.y;
    x[6]=E.z;  y[6]=E.w;  z[6]=F.x;
    x[7]=F.y;  y[7]=F.z;  z[7]=F.w;
  }
  float lx=x[0],hx=x[0],ly=y[0],hy=y[0],lz=z[0],hz=z[0];
  #pragma unroll
  for (int j = 1; j < 8; j++){
    lx=fminf(lx,x[j]); hx=fmaxf(hx,x[j]);
    ly=fminf(ly,y[j]); hy=fmaxf(hy,y[j]);
    lz=fminf(lz,z[j]); hz=fmaxf(hz,z[j]);
  }
  #pragma unroll
  for (int off = 1; off < 64; off <<= 1){
    lx=fminf(lx,__shfl_xor(lx,off)); hx=fmaxf(hx,__shfl_xor(hx,off));
    ly=fminf(ly,__shfl_xor(ly,off)); hy=fmaxf(hy,__shfl_xor(hy,off));
    lz=fminf(lz,__shfl_xor(lz,off)); hz=fmaxf(hz,__shfl_xor(hz,off));
  }
  if (lane == 0){
    rbb[wid]=lx; rbb[16+wid]=hx; rbb[32+wid]=ly; rbb[48+wid]=hy; rbb[64+wid]=lz; rbb[80+wid]=hz;
  }
  // zero histogram
  for (int i = tid; i < NN; i += 1024) curs[i] = 0;
  __syncthreads();
  #pragma unroll
  for (int i = 0; i < 16; i++){
    lx=fminf(lx,rbb[i]); hx=fmaxf(hx,rbb[16+i]);
    ly=fminf(ly,rbb[32+i]); hy=fmaxf(hy,rbb[48+i]);
    lz=fminf(lz,rbb[64+i]); hz=fmaxf(hz,rbb[80+i]);
  }
  float sx = 1023.0f/fmaxf(hx-lx,1e-20f);
  float sy = 1023.0f/fmaxf(hy-ly,1e-20f);
  float sz = 1023.0f/fmaxf(hz-lz,1e-20f);
  unsigned bkt[8];
  #pragma unroll
  for (int j = 0; j < 8; j++){
    int qx = (int)((x[j]-lx)*sx); qx = qx < 0 ? 0 : (qx > 1023 ? 1023 : qx);
    int qy = (int)((y[j]-ly)*sy); qy = qy < 0 ? 0 : (qy > 1023 ? 1023 : qy);
    int qz = (int)((z[j]-lz)*sz); qz = qz < 0 ? 0 : (qz > 1023 ? 1023 : qz);
    unsigned code = mspread((unsigned)qx) | (mspread((unsigned)qy) << 1) | (mspread((unsigned)qz) << 2);
    bkt[j] = code >> 17;            // top 13 of 30 bits -> 8192 buckets
    atomicAdd(&curs[bkt[j]], 1u);
  }
  __syncthreads();
  // hierarchical exclusive scan of curs[8192]
  unsigned v[8]; unsigned s = 0;
  #pragma unroll
  for (int j = 0; j < 8; j++){ v[j] = curs[tid*8 + j]; s += v[j]; }
  unsigned inc = s;
  #pragma unroll
  for (int off = 1; off < 64; off <<= 1){
    unsigned o = __shfl_up(inc, off);
    if (lane >= off) inc += o;
  }
  if (lane == 63) wsum[wid] = inc;
  __syncthreads();
  if (tid == 0){
    unsigned r = 0;
    #pragma unroll
    for (int i = 0; i < 16; i++){ unsigned t = wsum[i]; wsum[i] = r; r += t; }
  }
  __syncthreads();
  unsigned run = wsum[wid] + inc - s;   // exclusive prefix of this thread's 8-chunk
  #pragma unroll
  for (int j = 0; j < 8; j++){ curs[tid*8 + j] = run; run += v[j]; }
  __syncthreads();
  // scatter
  #pragma unroll
  for (int j = 0; j < 8; j++){
    unsigned pos = atomicAdd(&curs[bkt[j]], 1u);
    psx[b*NN + pos] = x[j];
    psy[b*NN + pos] = y[j];
    psz[b*NN + pos] = z[j];
    iorig[b*NN + pos] = tid*8 + j;
  }
}

// ---------------- DPP helpers ----------------
template<int C>
__device__ __forceinline__ float dpp_maxf(float v){
  int t = __builtin_amdgcn_update_dpp(0, f2i(v), C, 0xF, 0xF, true);
  return fmaxf(v, i2f(t));
}
template<int C>
__device__ __forceinline__ unsigned dpp_minu(unsigned v){
  unsigned t = (unsigned)__builtin_amdgcn_update_dpp(-1, (int)v, C, 0xF, 0xF, false);
  return v < t ? v : t;
}

// ---------------- FPS: Morton-sorted + PER-LANE bbox pruning ----------------
// R7: (1) NO per-pick global stores — tid0 previously wrote fps_idx + 3 output
// coords each pick, forcing wave 0 to drain vmcnt(0) at every per-pick barrier
// (all 16 waves wait). Now far goes to an LDS ring (farbuf) and outputs are
// batch-written in an epilogue (bit-identical values). (2) reduce cell widened
// to 4 sub-slots (w&3): 8-way -> 4-way same-address LDS-atomic serialization;
// merged by 3 compares post-barrier. Same 3-rotation reset protocol (reset
// slot is 2 barriers past its last read).
__global__ __launch_bounds__(1024, 1) void fps_kernel(const float* xyzf,
    const float* psx, const float* psy, const float* psz, const int* iorig,
    int* fps_idx, void* d_out, const int* flag){
  int b = blockIdx.x, tid = threadIdx.x;
  const float* xb = xyzf + (size_t)b*NN*3;
  __shared__ float sxyz4[NN*4];            // 128 KiB, [NN][4] padded
  __shared__ int farbuf[SS];               // 8 KiB pick ring
  __shared__ unsigned long long rk[3][4];
  for (int i = tid; i < NN; i += 1024){
    const float* p = xb + (size_t)i*3;
    float4 v; v.x = p[0]; v.y = p[1]; v.z = p[2]; v.w = 0.f;
    *(float4*)&sxyz4[(size_t)i*4] = v;
  }
  if (tid < 12) ((unsigned long long*)rk)[tid] = 0ull;
  f32x2_t px2[4], py2[4], pz2[4], dmin2[4];
  int io[8];
  {
    const float4* qx = (const float4*)(psx + b*NN + tid*8);
    const float4* qy = (const float4*)(psy + b*NN + tid*8);
    const float4* qz = (const float4*)(psz + b*NN + tid*8);
    float4 a, c;
    a = qx[0]; c = qx[1];
    px2[0]=(f32x2_t){a.x,a.y}; px2[1]=(f32x2_t){a.z,a.w}; px2[2]=(f32x2_t){c.x,c.y}; px2[3]=(f32x2_t){c.z,c.w};
    a = qy[0]; c = qy[1];
    py2[0]=(f32x2_t){a.x,a.y}; py2[1]=(f32x2_t){a.z,a.w}; py2[2]=(f32x2_t){c.x,c.y}; py2[3]=(f32x2_t){c.z,c.w};
    a = qz[0]; c = qz[1];
    pz2[0]=(f32x2_t){a.x,a.y}; pz2[1]=(f32x2_t){a.z,a.w}; pz2[2]=(f32x2_t){c.x,c.y}; pz2[3]=(f32x2_t){c.z,c.w};
    const int4* qi = (const int4*)(iorig + b*NN + tid*8);
    int4 i0 = qi[0], i1 = qi[1];
    io[0]=i0.x; io[1]=i0.y; io[2]=i0.z; io[3]=i0.w;
    io[4]=i1.x; io[5]=i1.y; io[6]=i1.z; io[7]=i1.w;
  }
  #pragma unroll
  for (int q = 0; q < 4; q++) dmin2[q] = (f32x2_t){1e10f, 1e10f};
  // per-lane bbox over the lane's 8 Morton-consecutive points
  float llx, lhx, lly, lhy, llz, lhz;
  {
    llx = fminf(fminf(px2[0].x,px2[0].y), fminf(px2[1].x,px2[1].y));
    llx = fminf(llx, fminf(fminf(px2[2].x,px2[2].y), fminf(px2[3].x,px2[3].y)));
    lhx = fmaxf(fmaxf(px2[0].x,px2[0].y), fmaxf(px2[1].x,px2[1].y));
    lhx = fmaxf(lhx, fmaxf(fmaxf(px2[2].x,px2[2].y), fmaxf(px2[3].x,px2[3].y)));
    lly = fminf(fminf(py2[0].x,py2[0].y), fminf(py2[1].x,py2[1].y));
    lly = fminf(lly, fminf(fminf(py2[2].x,py2[2].y), fminf(py2[3].x,py2[3].y)));
    lhy = fmaxf(fmaxf(py2[0].x,py2[0].y), fmaxf(py2[1].x,py2[1].y));
    lhy = fmaxf(lhy, fmaxf(fmaxf(py2[2].x,py2[2].y), fmaxf(py2[3].x,py2[3].y)));
    llz = fminf(fminf(pz2[0].x,pz2[0].y), fminf(pz2[1].x,pz2[1].y));
    llz = fminf(llz, fminf(fminf(pz2[2].x,pz2[2].y), fminf(pz2[3].x,pz2[3].y)));
    lhz = fmaxf(fmaxf(pz2[0].x,pz2[0].y), fmaxf(pz2[1].x,pz2[1].y));
    lhz = fmaxf(lhz, fmaxf(fmaxf(pz2[2].x,pz2[2].y), fmaxf(pz2[3].x,pz2[3].y)));
  }
  __syncthreads();
  int far = 0;
  int ln = tid & 63, w = tid >> 6;
  unsigned cached_lo = 0u, cached_hi = 0u;
  float lmax = 1e10f;                      // lane's max dmin over its 8 points
  int rot = 0;
  for (int s = 0; s < SS; s++){
    int rotn = rot + 1; if (rotn == 3) rotn = 0;
    float4 cf = *(const float4*)&sxyz4[(size_t)far*4];
    float cx = cf.x, cy = cf.y, cz = cf.z;
    if (tid == 0) farbuf[s] = far;                       // LDS only — no VMEM in loop
    if (tid >= 64 && tid < 68) rk[rotn][tid - 64] = 0ull; // slot quiescent since s-2
    float dxl = fmaxf(fmaxf(llx - cx, cx - lhx), 0.f);
    float dyl = fmaxf(fmaxf(lly - cy, cy - lhy), 0.f);
    float dzl = fmaxf(fmaxf(llz - cz, cz - lhz), 0.f);
    float d2l = (dxl*dxl + dyl*dyl + dzl*dzl) * 0.99999f;
    bool upd = (s == 0) || __any(d2l < lmax);
    if (upd){
      f32x2_t cx2 = (f32x2_t){cx, cx}, cy2 = (f32x2_t){cy, cy}, cz2 = (f32x2_t){cz, cz};
      bool ch = false;
      {
        #pragma clang fp contract(off)
        #pragma unroll
        for (int q = 0; q < 4; q++){
          f32x2_t dx = px2[q] - cx2, dy = py2[q] - cy2, dz = pz2[q] - cz2;
          f32x2_t t = dx*dx;
          t = t + dy*dy;
          t = t + dz*dz;
          ch = ch | (t.x < dmin2[q].x) | (t.y < dmin2[q].y);
          dmin2[q].x = fminf(dmin2[q].x, t.x);
          dmin2[q].y = fminf(dmin2[q].y, t.y);
        }
      }
      if (__any(ch)){
        float m0 = fmaxf(fmaxf(dmin2[0].x, dmin2[0].y), fmaxf(dmin2[1].x, dmin2[1].y));
        float m1 = fmaxf(fmaxf(dmin2[2].x, dmin2[2].y), fmaxf(dmin2[3].x, dmin2[3].y));
        float lm = fmaxf(m0, m1);
        lmax = lm;                         // refresh lane bound (free byproduct)
        lm = dpp_maxf<0x111>(lm); lm = dpp_maxf<0x112>(lm);
        lm = dpp_maxf<0x114>(lm); lm = dpp_maxf<0x118>(lm);
        lm = dpp_maxf<0x142>(lm); lm = dpp_maxf<0x143>(lm);
        float wmax = i2f(__builtin_amdgcn_readlane(f2i(lm), 63));
        unsigned cand = 0xFFFFFFFFu;
        #pragma unroll
        for (int q = 0; q < 4; q++){
          if (dmin2[q].x == wmax){ unsigned u = (unsigned)io[2*q];   cand = u < cand ? u : cand; }
          if (dmin2[q].y == wmax){ unsigned u = (unsigned)io[2*q+1]; cand = u < cand ? u : cand; }
        }
        cand = dpp_minu<0x111>(cand); cand = dpp_minu<0x112>(cand);
        cand = dpp_minu<0x114>(cand); cand = dpp_minu<0x118>(cand);
        cand = dpp_minu<0x142>(cand); cand = dpp_minu<0x143>(cand);
        unsigned cmin = (unsigned)__builtin_amdgcn_readlane((int)cand, 63);
        cached_hi = (unsigned)f2i(wmax);
        cached_lo = ~cmin;
      }
    }
    if (ln == 63)
      atomicMax(&rk[rot][w & 3], (((unsigned long long)cached_hi) << 32) | cached_lo);
    __syncthreads();
    unsigned long long k0 = rk[rot][0], k1 = rk[rot][1];
    unsigned long long k2 = rk[rot][2], k3 = rk[rot][3];
    unsigned long long ka = (k1 > k0) ? k1 : k0;
    unsigned long long kb = (k3 > k2) ? k3 : k2;
    unsigned long long kk = (kb > ka) ? kb : ka;
    far = (int)(~(unsigned)kk);
    rot = rotn;
  }
  __syncthreads();
  // epilogue: batched output write (identical values, off the per-pick path)
  bool isf32 = (*flag != 0);
  float* outf = (float*)d_out; unsigned short* outh = (unsigned short*)d_out;
  for (int s = tid; s < SS; s += 1024){
    int f = farbuf[s];
    fps_idx[b*SS + s] = f;
    float4 c = *(const float4*)&sxyz4[(size_t)f*4];
    size_t o = ((size_t)b*SS + s)*3;
    if (isf32){ outf[o] = c.x; outf[o+1] = c.y; outf[o+2] = c.z; }
    else { outh[o] = f2bf(c.x); outh[o+1] = f2bf(c.y); outh[o+2] = f2bf(c.z); }
  }
}

// ---------------- kNN: radix-histogram selection, coalesced planar loads ----------------
__global__ __launch_bounds__(256) void knn_kernel(
    const float* psx, const float* psy, const float* psz, const int* ior,
    const float* xyzf, const int* fps_idx, int* knn){
  int cg = blockIdx.x;
  int b = cg >> 11;
  int tid = threadIdx.x;
  const float* xb = xyzf + (size_t)b*NN*3;
  __shared__ unsigned hist[4096];
  __shared__ unsigned long long cand[512];
  __shared__ unsigned psum[256];
  __shared__ unsigned exbase[64];
  __shared__ float scc[3];
  __shared__ int sB, sBase, sCl, sCc;
  __shared__ unsigned long long rmin[4];
  __shared__ unsigned long long swin;

  if (tid == 0){
    int f = fps_idx[cg];
    scc[0] = xb[f*3]; scc[1] = xb[f*3+1]; scc[2] = xb[f*3+2];
    sCl = 0; sCc = 0;
  }
  #pragma unroll
  for (int i = 0; i < 16; i++) hist[tid*16 + i] = 0;
  __syncthreads();
  float cx = scc[0], cy = scc[1], cz = scc[2];

  float dv[32]; int iv[32];
  const float4* qx = (const float4*)(psx + b*NN);
  const float4* qy = (const float4*)(psy + b*NN);
  const float4* qz = (const float4*)(psz + b*NN);
  const int4*   qi = (const int4*)(ior + b*NN);
  {
    #pragma clang fp contract(off)
    #pragma unroll
    for (int k = 0; k < 8; k++){
      float4 X = qx[k*256 + tid];
      float4 Y = qy[k*256 + tid];
      float4 Z = qz[k*256 + tid];
      int4   I = qi[k*256 + tid];
      float xs_[4] = {X.x, X.y, X.z, X.w};
      float ys_[4] = {Y.x, Y.y, Y.z, Y.w};
      float zs_[4] = {Z.x, Z.y, Z.z, Z.w};
      int   is_[4] = {I.x, I.y, I.z, I.w};
      #pragma unroll
      for (int r = 0; r < 4; r++){
        float dx = cx - xs_[r], dy = cy - ys_[r], dz = cz - zs_[r];
        dv[k*4 + r] = dx*dx + dy*dy + dz*dz;
        iv[k*4 + r] = is_[r];
      }
    }
  }
  #pragma unroll
  for (int t = 0; t < 32; t++)
    atomicAdd(&hist[((unsigned)f2i(dv[t])) >> 20], 1u);
  __syncthreads();
  unsigned lsum = 0;
  #pragma unroll
  for (int i = 0; i < 16; i++) lsum += hist[tid*16 + i];
  psum[tid] = lsum;
  __syncthreads();
  if (tid < 64){
    unsigned s4 = psum[tid*4] + psum[tid*4+1] + psum[tid*4+2] + psum[tid*4+3];
    unsigned inc = s4;
    #pragma unroll
    for (int off = 1; off < 64; off <<= 1){
      unsigned o = __shfl_up(inc, off);
      if (tid >= off) inc += o;
    }
    exbase[tid] = inc - s4;
  }
  __syncthreads();
  {
    int g4 = tid >> 2;
    unsigned ex = exbase[g4];
    for (int j = g4*4; j < tid; j++) ex += psum[j];
    unsigned run = ex;
    #pragma unroll
    for (int i = 0; i < 16; i++){
      unsigned c = hist[tid*16 + i];
      if (run < 32u && run + c >= 32u){ sB = tid*16 + i; sBase = (int)run; }
      run += c;
    }
  }
  __syncthreads();
  int Bbin = sB, base = sBase;
  int out = cg << 5;
  #pragma unroll
  for (int t = 0; t < 32; t++){
    unsigned bits = (unsigned)f2i(dv[t]);
    unsigned hb = bits >> 20;
    int idx = iv[t];
    if ((int)hb < Bbin){
      int sl = atomicAdd(&sCl, 1);
      knn[out + sl] = idx;
    } else if ((int)hb == Bbin){
      int c = atomicAdd(&sCc, 1);
      if (c < 512) cand[c] = (((unsigned long long)bits) << 32) | (unsigned)idx;
    }
  }
  __syncthreads();
  int cc = sCc; if (cc > 512) cc = 512;
  int r = 32 - base;
  for (int round = 0; round < r; round++){
    unsigned long long lm = ~0ull;
    for (int i = tid; i < cc; i += 256){
      unsigned long long v = cand[i];
      if (v < lm) lm = v;
    }
    #pragma unroll
    for (int off = 1; off < 64; off <<= 1){
      unsigned long long o = __shfl_xor(lm, off);
      if (o < lm) lm = o;
    }
    if ((tid & 63) == 0) rmin[tid >> 6] = lm;
    __syncthreads();
    if (tid == 0){
      unsigned long long m = rmin[0];
      #pragma unroll
      for (int q = 1; q < 4; q++) if (rmin[q] < m) m = rmin[q];
      swin = m;
      knn[out + base + round] = (int)(unsigned)m;
    }
    __syncthreads();
    unsigned long long m = swin;
    for (int i = tid; i < cc; i += 256)
      if (cand[i] == m) cand[i] = ~0ull;
    __syncthreads();
  }
}

// ---------------- materialized MLP passes (BN finalize folded in) ----------------
__device__ __forceinline__ bf16x8_t bfrag(const unsigned short* wp, int f, int lane){
  return *(const bf16x8_t*)(wp + ((size_t)f << 9) + (lane << 3));
}
__device__ __forceinline__ bf16x8_t bn_frag(bf16x8_t v, const float* a, const float* c, int kbase){
  float4 a0 = *(const float4*)(a + kbase); float4 a1 = *(const float4*)(a + kbase + 4);
  float4 c0 = *(const float4*)(c + kbase); float4 c1 = *(const float4*)(c + kbase + 4);
  float av[8] = {a0.x,a0.y,a0.z,a0.w,a1.x,a1.y,a1.z,a1.w};
  float cv[8] = {c0.x,c0.y,c0.z,c0.w,c1.x,c1.y,c1.z,c1.w};
  bf16x8_t r;
  #pragma unroll
  for (int j = 0; j < 8; j++)
    r[j] = (short)f2bf(fmaxf(bf2f((unsigned short)v[j])*av[j] + cv[j], 0.f));
  return r;
}

template<int TILES>
__global__ __launch_bounds__(256) void passA(
    const float* __restrict__ xyzf, const unsigned short* __restrict__ ptsb,
    const int* __restrict__ fpsi, const int* __restrict__ knn,
    const unsigned short* __restrict__ w0p,
    unsigned short* __restrict__ y0g, float* osum, float* osq)
{
  __shared__ unsigned short xb0[64*104];
  __shared__ unsigned short st[64*72];
  __shared__ float sacc[128];
  int tid = threadIdx.x, lane = tid & 63, w = tid >> 6;
  int l15 = lane & 15, quad = lane >> 4;
  float ssum[4], ssq[4];
  #pragma unroll
  for (int c = 0; c < 4; c++){ ssum[c] = 0.f; ssq[c] = 0.f; }
  if (tid < 128) sacc[tid] = 0.f;
  __syncthreads();

  for (int t = 0; t < TILES; t++){
    int row0 = (blockIdx.x * TILES + t) * 64;
    {
      int r = tid >> 2, p = tid & 3;
      int g = row0 + r;
      int bq = g >> 16, s = (g >> 5) & 2047;
      int n = knn[g];
      const bf16x8_t* pr = (const bf16x8_t*)(ptsb + (((size_t)bq*NN + n) << 6));
      *(bf16x8_t*)&xb0[r*104 + p*16]     = pr[p*2];
      *(bf16x8_t*)&xb0[r*104 + p*16 + 8] = pr[p*2 + 1];
      if (p == 3){
        const float* xbp = xyzf + (size_t)bq*NN*3;
        int f = fpsi[(bq << 11) + s];
        float dx = xbp[n*3]   - xbp[f*3];
        float dy = xbp[n*3+1] - xbp[f*3+1];
        float dz = xbp[n*3+2] - xbp[f*3+2];
        bf16x8_t v = {(short)f2bf(dx), (short)f2bf(dy), (short)f2bf(dz), 0,0,0,0,0};
        bf16x8_t z = {0,0,0,0,0,0,0,0};
        *(bf16x8_t*)&xb0[r*104 + 64] = v;
        *(bf16x8_t*)&xb0[r*104 + 72] = z;
        *(bf16x8_t*)&xb0[r*104 + 80] = z;
        *(bf16x8_t*)&xb0[r*104 + 88] = z;
      }
    }
    bf16x8_t a0[3];
    #pragma unroll
    for (int ks = 0; ks < 3; ks++)
      a0[ks] = *(const bf16x8_t*)&xb0[(w*16 + l15)*104 + ks*32 + quad*8];
    #pragma unroll
    for (int ct = 0; ct < 4; ct++){
      f32x4_t a = {0.f,0.f,0.f,0.f};
      #pragma unroll
      for (int ks = 0; ks < 3; ks++)
        a = __builtin_amdgcn_mfma_f32_16x16x32_bf16(a0[ks], bfrag(w0p, ct*3+ks, lane), a, 0, 0, 0);
      #pragma unroll
      for (int r = 0; r < 4; r++){
        float v = a[r]; ssum[ct] += v; ssq[ct] += v*v;
        st[(w*16 + quad*4 + r)*72 + ct*16 + l15] = f2bf(v);
      }
    }
    __syncthreads();
    #pragma unroll
    for (int p = 0; p < 2; p++){
      int idx = p*2048 + tid*8; int r = idx >> 6; int c = idx & 63;
      *(bf16x8_t*)(y0g + (size_t)row0*64 + idx) = *(const bf16x8_t*)&st[r*72 + c];
    }
    __syncthreads();
  }
  #pragma unroll
  for (int c = 0; c < 4; c++){
    ssum[c] += __shfl_xor(ssum[c], 16); ssum[c] += __shfl_xor(ssum[c], 32);
    ssq [c] += __shfl_xor(ssq [c], 16); ssq [c] += __shfl_xor(ssq [c], 32);
  }
  if (quad == 0){
    #pragma unroll
    for (int c = 0; c < 4; c++){
      atomicAdd(&sacc[c*16 + l15], ssum[c]);
      atomicAdd(&sacc[64 + c*16 + l15], ssq[c]);
    }
  }
  __syncthreads();
  if (tid < 64){
    atomicAdd(&osum[tid], sacc[tid]);
    atomicAdd(&osq [tid], sacc[64 + tid]);
  }
}

template<int TILES>
__global__ __launch_bounds__(256) void passB(
    const unsigned short* __restrict__ y0g, const unsigned short* __restrict__ w1p,
    const float* __restrict__ stats, const float* __restrict__ gbf,
    unsigned short* __restrict__ y1g, float* osum, float* osq)
{
  __shared__ unsigned short st[64*136];
  __shared__ float sacc[256];
  __shared__ __align__(16) float sbn[128];
  int tid = threadIdx.x, lane = tid & 63, w = tid >> 6;
  int l15 = lane & 15, quad = lane >> 4;
  float ssum[8], ssq[8];
  #pragma unroll
  for (int c = 0; c < 8; c++){ ssum[c] = 0.f; ssq[c] = 0.f; }
  sacc[tid] = 0.f;
  if (tid < 64){
    const float invM = 1.0f/262144.0f;
    float mu = stats[tid]*invM;
    float var = fmaxf(stats[64+tid]*invM - mu*mu, 0.f);
    float inv = 1.0f/sqrtf(var + 1e-5f);
    float av = gbf[tid]*inv;
    sbn[tid] = av; sbn[64+tid] = gbf[64+tid] - mu*av;
  }
  __syncthreads();

  for (int t = 0; t < TILES; t++){
    int row0 = (blockIdx.x * TILES + t) * 64;
    int row = row0 + w*16 + l15;
    bf16x8_t a1[2];
    #pragma unroll
    for (int ks = 0; ks < 2; ks++){
      bf16x8_t v = *(const bf16x8_t*)(y0g + (size_t)row*64 + ks*32 + quad*8);
      a1[ks] = bn_frag(v, sbn, sbn + 64, ks*32 + quad*8);
    }
    #pragma unroll
    for (int ct = 0; ct < 8; ct++){
      f32x4_t a = {0.f,0.f,0.f,0.f};
      #pragma unroll
      for (int ks = 0; ks < 2; ks++)
        a = __builtin_amdgcn_mfma_f32_16x16x32_bf16(a1[ks], bfrag(w1p, ct*2+ks, lane), a, 0, 0, 0);
      #pragma unroll
      for (int r = 0; r < 4; r++){
        float v = a[r]; ssum[ct] += v; ssq[ct] += v*v;
        st[(w*16 + quad*4 + r)*136 + ct*16 + l15] = f2bf(v);
      }
    }
    __syncthreads();
    #pragma unroll
    for (int p = 0; p < 4; p++){
      int idx = p*2048 + tid*8; int r = idx >> 7; int c = idx & 127;
      *(bf16x8_t*)(y1g + (size_t)row0*128 + idx) = *(const bf16x8_t*)&st[r*136 + c];
    }
    __syncthreads();
  }
  #pragma unroll
  for (int c = 0; c < 8; c++){
    ssum[c] += __shfl_xor(ssum[c], 16); ssum[c] += __shfl_xor(ssum[c], 32);
    ssq [c] += __shfl_xor(ssq [c], 16); ssq [c] += __shfl_xor(ssq [c], 32);
  }
  if (quad == 0){
    #pragma unroll
    for (int c = 0; c < 8; c++){
      atomicAdd(&sacc[c*16 + l15], ssum[c]);
      atomicAdd(&sacc[128 + c*16 + l15], ssq[c]);
    }
  }
  __syncthreads();
  if (tid < 128){
    atomicAdd(&osum[tid], sacc[tid]);
    atomicAdd(&osq [tid], sacc[128 + tid]);
  }
}

template<int TILES>
__global__ __launch_bounds__(256) void passC(
    const unsigned short* __restrict__ y1g, const unsigned short* __restrict__ w2p,
    const float* __restrict__ stats, const float* __restrict__ gbf,
    float* osum, float* osq)
{
  __shared__ float sacc[512];
  __shared__ __align__(16) float sbn[256];
  int tid = threadIdx.x, lane = tid & 63, w = tid >> 6;
  int l15 = lane & 15, quad = lane >> 4;
  float ssum[16], ssq[16];
  #pragma unroll
  for (int c = 0; c < 16; c++){ ssum[c] = 0.f; ssq[c] = 0.f; }
  sacc[tid] = 0.f; sacc[tid + 256] = 0.f;
  if (tid < 128){
    const float invM = 1.0f/262144.0f;
    float mu = stats[128+tid]*invM;
    float var = fmaxf(stats[256+tid]*invM - mu*mu, 0.f);
    float inv = 1.0f/sqrtf(var + 1e-5f);
    float av = gbf[128+tid]*inv;
    sbn[tid] = av; sbn[128+tid] = gbf[256+tid] - mu*av;
  }
  __syncthreads();

  for (int t = 0; t < TILES; t++){
    int row0 = (blockIdx.x * TILES + t) * 64;
    int row = row0 + w*16 + l15;
    bf16x8_t a2[4];
    #pragma unroll
    for (int ks = 0; ks < 4; ks++){
      bf16x8_t v = *(const bf16x8_t*)(y1g + (size_t)row*128 + ks*32 + quad*8);
      a2[ks] = bn_frag(v, sbn, sbn + 128, ks*32 + quad*8);
    }
    #pragma unroll
    for (int ct = 0; ct < 16; ct++){
      f32x4_t a = {0.f,0.f,0.f,0.f};
      #pragma unroll
      for (int ks = 0; ks < 4; ks++)
        a = __builtin_amdgcn_mfma_f32_16x16x32_bf16(a2[ks], bfrag(w2p, ct*4+ks, lane), a, 0, 0, 0);
      #pragma unroll
      for (int r = 0; r < 4; r++){ float v = a[r]; ssum[ct] += v; ssq[ct] += v*v; }
    }
  }
  #pragma unroll
  for (int c = 0; c < 16; c++){
    ssum[c] += __shfl_xor(ssum[c], 16); ssum[c] += __shfl_xor(ssum[c], 32);
    ssq [c] += __shfl_xor(ssq [c], 16); ssq [c] += __shfl_xor(ssq [c], 32);
  }
  if (quad == 0){
    #pragma unroll
    for (int c = 0; c < 16; c++){
      atomicAdd(&sacc[c*16 + l15], ssum[c]);
      atomicAdd(&sacc[256 + c*16 + l15], ssq[c]);
    }
  }
  __syncthreads();
  if (tid < 256){
    atomicAdd(&osum[tid], sacc[tid]);
    atomicAdd(&osq [tid], sacc[256 + tid]);
  }
}

__global__ __launch_bounds__(256) void passD(
    const unsigned short* __restrict__ y1g, const unsigned short* __restrict__ w2p,
    const float* __restrict__ stats, const float* __restrict__ gbf,
    void* d_out, const int* __restrict__ flag)
{
  __shared__ float smax[1024];
  __shared__ __align__(16) float sbn[768];  // a1[128] c1[128] a2[256] c2[256]
  int tid = threadIdx.x, lane = tid & 63, w = tid >> 6;
  int l15 = lane & 15, quad = lane >> 4;
  {
    const float invM = 1.0f/262144.0f;
    if (tid < 128){
      float mu = stats[128+tid]*invM;
      float var = fmaxf(stats[256+tid]*invM - mu*mu, 0.f);
      float inv = 1.0f/sqrtf(var + 1e-5f);
      float av = gbf[128+tid]*inv;
      sbn[tid] = av; sbn[128+tid] = gbf[256+tid] - mu*av;
    }
    float mu2 = stats[384+tid]*invM;
    float var2 = fmaxf(stats[640+tid]*invM - mu2*mu2, 0.f);
    float inv2 = 1.0f/sqrtf(var2 + 1e-5f);
    float av2 = gbf[384+tid]*inv2;
    sbn[256+tid] = av2; sbn[512+tid] = gbf[640+tid] - mu2*av2;
  }
  __syncthreads();
  int row0 = blockIdx.x * 64;
  int row = row0 + w*16 + l15;
  bf16x8_t a2[4];
  #pragma unroll
  for (int ks = 0; ks < 4; ks++){
    bf16x8_t v = *(const bf16x8_t*)(y1g + (size_t)row*128 + ks*32 + quad*8);
    a2[ks] = bn_frag(v, sbn, sbn + 128, ks*32 + quad*8);
  }
  #pragma unroll
  for (int ct = 0; ct < 16; ct++){
    f32x4_t a = {0.f,0.f,0.f,0.f};
    #pragma unroll
    for (int ks = 0; ks < 4; ks++)
      a = __builtin_amdgcn_mfma_f32_16x16x32_bf16(a2[ks], bfrag(w2p, ct*4+ks, lane), a, 0, 0, 0);
    int o = ct*16 + l15;
    float ga = sbn[256 + o], gc = sbn[512 + o];
    float m = fmaxf(fmaxf(a[0]*ga + gc, a[1]*ga + gc), fmaxf(a[2]*ga + gc, a[3]*ga + gc));
    m = fmaxf(m, __shfl_xor(m, 16));
    m = fmaxf(m, __shfl_xor(m, 32));
    if (quad == 0) smax[w*256 + o] = m;
  }
  __syncthreads();
  float v0 = fmaxf(fmaxf(smax[tid], smax[256 + tid]), 0.f);
  float v1 = fmaxf(fmaxf(smax[512 + tid], smax[768 + tid]), 0.f);
  int cg = blockIdx.x * 2;
  bool isf32 = (*flag != 0);
  int b0 = cg >> 11, s0 = cg & 2047;
  int b1 = (cg+1) >> 11, s1 = (cg+1) & 2047;
  size_t o0 = (size_t)BB*SS*3 + (((size_t)(b0*256 + tid)) << 11) + s0;
  size_t o1 = (size_t)BB*SS*3 + (((size_t)(b1*256 + tid)) << 11) + s1;
  if (isf32){ ((float*)d_out)[o0] = v0; ((float*)d_out)[o1] = v1; }
  else { ((unsigned short*)d_out)[o0] = f2bf(v0); ((unsigned short*)d_out)[o1] = f2bf(v1); }
}

// ---------------- workspace layout (bytes) ----------------
#define OFF_FLAG   0u
#define OFF_FPS    256u
#define OFF_KNN    33024u
#define OFF_STATS  1081600u
#define OFF_XYZF   1088768u
#define OFF_GB     1481984u
#define OFF_W0P    1485568u
#define OFF_W1P    1497856u
#define OFF_W2P    1514240u
#define OFF_PTSB   1579776u
#define OFF_Y0     5774336u
#define OFF_Y1     39328768u
#define OFF_PSX    (OFF_Y1)
#define OFF_PSY    (OFF_Y1 + 131072u)
#define OFF_PSZ    (OFF_Y1 + 262144u)
#define OFF_IOR    (OFF_Y1 + 393216u)

extern "C" void kernel_launch(void* const* d_in, const int* in_sizes, int n_in,
                              void* d_out, int out_size, void* d_ws, size_t ws_size,
                              hipStream_t stream){
  char* ws = (char*)d_ws;
  int*   flag  = (int*)(ws + OFF_FLAG);
  int*   fpsi  = (int*)(ws + OFF_FPS);
  int*   knn   = (int*)(ws + OFF_KNN);
  float* stats = (float*)(ws + OFF_STATS);
  float* xyzf  = (float*)(ws + OFF_XYZF);
  float* gbf   = (float*)(ws + OFF_GB);
  unsigned short* w0p = (unsigned short*)(ws + OFF_W0P);
  unsigned short* w1p = (unsigned short*)(ws + OFF_W1P);
  unsigned short* w2p = (unsigned short*)(ws + OFF_W2P);
  unsigned short* ptsb = (unsigned short*)(ws + OFF_PTSB);
  unsigned short* y0g = (unsigned short*)(ws + OFF_Y0);
  unsigned short* y1g = (unsigned short*)(ws + OFF_Y1);
  float* psx = (float*)(ws + OFF_PSX);
  float* psy = (float*)(ws + OFF_PSY);
  float* psz = (float*)(ws + OFF_PSZ);
  int*   ior = (int*)(ws + OFF_IOR);

  detect_kernel<<<1, 256, 0, stream>>>(d_in[1], flag);
  prep_kernel<<<1084, 256, 0, stream>>>(d_in[0], d_in[1], d_in[2], d_in[5], d_in[8],
                                        d_in[3], d_in[4], d_in[6], d_in[7], d_in[9], d_in[10],
                                        xyzf, ptsb, w0p, w1p, w2p, gbf, stats, flag);

  morton_sort<<<BB, 1024, 0, stream>>>(xyzf, psx, psy, psz, ior);
  fps_kernel<<<BB, 1024, 0, stream>>>(xyzf, psx, psy, psz, ior, fpsi, d_out, flag);
  knn_kernel<<<BB*SS, 256, 0, stream>>>(psx, psy, psz, ior, xyzf, fpsi, knn);

  passA<4><<<1024, 256, 0, stream>>>(xyzf, ptsb, fpsi, knn, w0p, y0g, stats + 0, stats + 64);
  passB<4><<<1024, 256, 0, stream>>>(y0g, w1p, stats, gbf, y1g, stats + 128, stats + 256);
  passC<4><<<1024, 256, 0, stream>>>(y1g, w2p, stats, gbf, stats + 384, stats + 640);
  passD<<<4096, 256, 0, stream>>>(y1g, w2p, stats, gbf, d_out, flag);
  (void)in_sizes; (void)n_in; (void)out_size; (void)ws_size;
}

// Round 8
// 1791.676 us; speedup vs baseline: 1.1193x; 1.1193x over previous
//
#include <hip/hip_runtime.h>

#define BB 4
#define NN 8192
#define CC 64
#define SS 2048
#define KK 32
#define MROWS (BB*SS*KK)   // 262144

typedef __attribute__((ext_vector_type(8))) short bf16x8_t;
typedef __attribute__((ext_vector_type(4))) float f32x4_t;
typedef __attribute__((ext_vector_type(2))) float f32x2_t;

__device__ __forceinline__ float bf2f(unsigned short u){
  union { unsigned int i; float f; } v; v.i = ((unsigned int)u) << 16; return v.f;
}
__device__ __forceinline__ unsigned short f2bf(float f){
  union { float f; unsigned int i; } v; v.f = f;
  unsigned int u = v.i;
  unsigned int r = (u + 0x7FFFu + ((u >> 16) & 1u)) >> 16;
  return (unsigned short)r;
}
__device__ __forceinline__ float i2f(int i){ union { int i; float f; } v; v.i = i; return v.f; }
__device__ __forceinline__ int f2i(float f){ union { float f; int i; } v; v.f = f; return v.i; }

// ---------------- dtype detection ----------------
__global__ void detect_kernel(const void* pts, int* flag){
  __shared__ int cnt;
  if (threadIdx.x == 0) cnt = 0;
  __syncthreads();
  unsigned short u = ((const unsigned short*)pts)[threadIdx.x];
  int e = (u >> 7) & 0xFF;
  if (e != 0 && (e < 112 || e > 143)) atomicAdd(&cnt, 1);
  __syncthreads();
  if (threadIdx.x == 0) *flag = (cnt > 32) ? 1 : 0;
}

// ---------------- prep: xyz convert + weight packs + stats zero ----------------
// R8: pts transpose moved into the fps dispatch (runs on CUs idle during fps).
__device__ __forceinline__ void pack_dev(const void* src, unsigned short* dst,
    int CTS, int KSTEPS, int IN, int remap, int idx, bool isf){
  int total = CTS*KSTEPS*512;
  if (idx >= total) return;
  int f = idx >> 9, lane = (idx >> 3) & 63, j = idx & 7;
  int ct = f / KSTEPS, ks = f % KSTEPS;
  int n = ct*16 + (lane & 15);
  int k = ks*32 + (lane >> 4)*8 + j;
  int ksrc;
  if (remap){ ksrc = (k < 64) ? (k + 3) : (k < 67 ? k - 64 : -1); }
  else      { ksrc = (k < IN) ? k : -1; }
  float v = 0.f;
  if (ksrc >= 0){
    size_t si = (size_t)n*IN + ksrc;
    v = isf ? ((const float*)src)[si] : bf2f(((const unsigned short*)src)[si]);
  }
  dst[idx] = f2bf(v);
}

__global__ __launch_bounds__(256) void prep_kernel(
    const void* xyz_in,
    const void* w0_in, const void* w1_in, const void* w2_in,
    const void* g0, const void* b0, const void* g1, const void* b1,
    const void* g2, const void* b2,
    float* xyzf,
    unsigned short* w0p, unsigned short* w1p, unsigned short* w2p,
    float* gbf, float* stats, const int* flag)
{
  int blk = blockIdx.x, tid = threadIdx.x;
  bool isf = (*flag != 0);
  if (blk < 384){
    int i = blk*256 + tid;
    if (i < BB*NN*3)
      xyzf[i] = isf ? ((const float*)xyz_in)[i] : bf2f(((const unsigned short*)xyz_in)[i]);
  } else if (blk < 388){
    int i = (blk - 384)*256 + tid;
    if (i < 896){
      const void* src; int off;
      if      (i < 64)  { src = g0; off = i; }
      else if (i < 128) { src = b0; off = i - 64; }
      else if (i < 256) { src = g1; off = i - 128; }
      else if (i < 384) { src = b1; off = i - 256; }
      else if (i < 640) { src = g2; off = i - 384; }
      else              { src = b2; off = i - 640; }
      gbf[i] = isf ? ((const float*)src)[off] : bf2f(((const unsigned short*)src)[off]);
      stats[i] = 0.f;
    }
  } else if (blk < 412){
    pack_dev(w0_in, w0p, 4, 3, 67, 1, (blk-388)*256 + tid, isf);
  } else if (blk < 444){
    pack_dev(w1_in, w1p, 8, 2, 64, 0, (blk-412)*256 + tid, isf);
  } else {
    pack_dev(w2_in, w2p, 16, 4, 128, 0, (blk-444)*256 + tid, isf);
  }
}

// ---------------- Morton 13-bit counting sort (one block per batch) ----------------
__device__ __forceinline__ unsigned mspread(unsigned v){
  v = (v | (v << 16)) & 0x030000FFu;
  v = (v | (v <<  8)) & 0x0300F00Fu;
  v = (v | (v <<  4)) & 0x030C30C3u;
  v = (v | (v <<  2)) & 0x09249249u;
  return v;
}
__global__ __launch_bounds__(1024) void morton_sort(const float* xyzf,
    float* psx, float* psy, float* psz, int* iorig){
  int b = blockIdx.x, tid = threadIdx.x;
  int lane = tid & 63, wid = tid >> 6;
  const float* xb = xyzf + (size_t)b*NN*3;
  __shared__ unsigned curs[NN];     // 32 KiB: histogram, then exclusive-prefix cursors
  __shared__ float rbb[96];
  __shared__ unsigned wsum[16];
  float x[8], y[8], z[8];
  {
    const float4* p4 = (const float4*)(xb + (size_t)tid*24);
    float4 A=p4[0],B2=p4[1],C=p4[2],D=p4[3],E=p4[4],F=p4[5];
    x[0]=A.x;  y[0]=A.y;  z[0]=A.z;
    x[1]=A.w;  y[1]=B2.x; z[1]=B2.y;
    x[2]=B2.z; y[2]=B2.w; z[2]=C.x;
    x[3]=C.y;  y[3]=C.z;  z[3]=C.w;
    x[4]=D.x;  y[4]=D.y;  z[4]=D.z;
    x[5]=D.w;  y[5]=E.x;  z[5]=E.y;
    x[6]=E.z;  y[6]=E.w;  z[6]=F.x;
    x[7]=F.y;  y[7]=F.z;  z[7]=F.w;
  }
  float lx=x[0],hx=x[0],ly=y[0],hy=y[0],lz=z[0],hz=z[0];
  #pragma unroll
  for (int j = 1; j < 8; j++){
    lx=fminf(lx,x[j]); hx=fmaxf(hx,x[j]);
    ly=fminf(ly,y[j]); hy=fmaxf(hy,y[j]);
    lz=fminf(lz,z[j]); hz=fmaxf(hz,z[j]);
  }
  #pragma unroll
  for (int off = 1; off < 64; off <<= 1){
    lx=fminf(lx,__shfl_xor(lx,off)); hx=fmaxf(hx,__shfl_xor(hx,off));
    ly=fminf(ly,__shfl_xor(ly,off)); hy=fmaxf(hy,__shfl_xor(hy,off));
    lz=fminf(lz,__shfl_xor(lz,off)); hz=fmaxf(hz,__shfl_xor(hz,off));
  }
  if (lane == 0){
    rbb[wid]=lx; rbb[16+wid]=hx; rbb[32+wid]=ly; rbb[48+wid]=hy; rbb[64+wid]=lz; rbb[80+wid]=hz;
  }
  // zero histogram
  for (int i = tid; i < NN; i += 1024) curs[i] = 0;
  __syncthreads();
  #pragma unroll
  for (int i = 0; i < 16; i++){
    lx=fminf(lx,rbb[i]); hx=fmaxf(hx,rbb[16+i]);
    ly=fminf(ly,rbb[32+i]); hy=fmaxf(hy,rbb[48+i]);
    lz=fminf(lz,rbb[64+i]); hz=fmaxf(hz,rbb[80+i]);
  }
  float sx = 1023.0f/fmaxf(hx-lx,1e-20f);
  float sy = 1023.0f/fmaxf(hy-ly,1e-20f);
  float sz = 1023.0f/fmaxf(hz-lz,1e-20f);
  unsigned bkt[8];
  #pragma unroll
  for (int j = 0; j < 8; j++){
    int qx = (int)((x[j]-lx)*sx); qx = qx < 0 ? 0 : (qx > 1023 ? 1023 : qx);
    int qy = (int)((y[j]-ly)*sy); qy = qy < 0 ? 0 : (qy > 1023 ? 1023 : qy);
    int qz = (int)((z[j]-lz)*sz); qz = qz < 0 ? 0 : (qz > 1023 ? 1023 : qz);
    unsigned code = mspread((unsigned)qx) | (mspread((unsigned)qy) << 1) | (mspread((unsigned)qz) << 2);
    bkt[j] = code >> 17;            // top 13 of 30 bits -> 8192 buckets
    atomicAdd(&curs[bkt[j]], 1u);
  }
  __syncthreads();
  // hierarchical exclusive scan of curs[8192]
  unsigned v[8]; unsigned s = 0;
  #pragma unroll
  for (int j = 0; j < 8; j++){ v[j] = curs[tid*8 + j]; s += v[j]; }
  unsigned inc = s;
  #pragma unroll
  for (int off = 1; off < 64; off <<= 1){
    unsigned o = __shfl_up(inc, off);
    if (lane >= off) inc += o;
  }
  if (lane == 63) wsum[wid] = inc;
  __syncthreads();
  if (tid == 0){
    unsigned r = 0;
    #pragma unroll
    for (int i = 0; i < 16; i++){ unsigned t = wsum[i]; wsum[i] = r; r += t; }
  }
  __syncthreads();
  unsigned run = wsum[wid] + inc - s;   // exclusive prefix of this thread's 8-chunk
  #pragma unroll
  for (int j = 0; j < 8; j++){ curs[tid*8 + j] = run; run += v[j]; }
  __syncthreads();
  // scatter
  #pragma unroll
  for (int j = 0; j < 8; j++){
    unsigned pos = atomicAdd(&curs[bkt[j]], 1u);
    psx[b*NN + pos] = x[j];
    psy[b*NN + pos] = y[j];
    psz[b*NN + pos] = z[j];
    iorig[b*NN + pos] = tid*8 + j;
  }
}

// ---------------- DPP helpers ----------------
template<int C>
__device__ __forceinline__ float dpp_maxf(float v){
  int t = __builtin_amdgcn_update_dpp(0, f2i(v), C, 0xF, 0xF, true);
  return fmaxf(v, i2f(t));
}
template<int C>
__device__ __forceinline__ unsigned dpp_minu(unsigned v){
  unsigned t = (unsigned)__builtin_amdgcn_update_dpp(-1, (int)v, C, 0xF, 0xF, false);
  return v < t ? v : t;
}

// ---------------- FPS (R6 body, proven) + co-scheduled pts transpose ----------------
// Blocks 0-3: FPS, one per batch (R6-exact: per-pick global stores by tid0,
// rk[3][2] reduce cell, per-lane bbox prune). Blocks 4-131: the points
// transpose (pts (B,C,N) -> ptsb (B,N,C) bf16), which only passA consumes —
// it runs on CUs that sit idle during the 4-CU FPS phase, making it free.
// Transpose blocks reuse sxyz4's LDS as their tile (they never run FPS code).
__global__ __launch_bounds__(1024, 1) void fps_kernel(const float* xyzf,
    const float* psx, const float* psy, const float* psz, const int* iorig,
    int* fps_idx, void* d_out, const int* flag,
    const void* pts_in, unsigned short* ptsb){
  int tid = threadIdx.x;
  __shared__ float sxyz4[NN*4];            // 128 KiB, [NN][4] padded (fps) / tile (transpose)
  __shared__ unsigned long long rk[3][2];
  if (blockIdx.x >= 4){
    // ---- pts transpose branch: 128 blocks x 1024 thr; 64ch x 256n tile ----
    int blk = blockIdx.x - 4;
    int b = blk >> 5, n0 = (blk & 31) * 256;
    bool isf = (*flag != 0);
    float (*tile)[257] = (float(*)[257])sxyz4;   // 64*257*4B = 65.8KB < 128KB
    #pragma unroll
    for (int k = 0; k < 16; k++){
      int idx = k*1024 + tid; int c = idx >> 8; int ni = idx & 255;
      size_t src = ((size_t)b*CC + c)*NN + n0 + ni;
      tile[c][ni] = isf ? ((const float*)pts_in)[src] : bf2f(((const unsigned short*)pts_in)[src]);
    }
    __syncthreads();
    #pragma unroll
    for (int k = 0; k < 16; k++){
      int idx = k*1024 + tid; int ni = idx >> 6; int c = idx & 63;
      ptsb[((size_t)b*NN + n0 + ni)*CC + c] = f2bf(tile[c][ni]);
    }
    return;
  }
  int b = blockIdx.x;
  const float* xb = xyzf + (size_t)b*NN*3;
  for (int i = tid; i < NN; i += 1024){
    const float* p = xb + (size_t)i*3;
    float4 v; v.x = p[0]; v.y = p[1]; v.z = p[2]; v.w = 0.f;
    *(float4*)&sxyz4[(size_t)i*4] = v;
  }
  if (tid < 6) ((unsigned long long*)rk)[tid] = 0ull;
  f32x2_t px2[4], py2[4], pz2[4], dmin2[4];
  int io[8];
  {
    const float4* qx = (const float4*)(psx + b*NN + tid*8);
    const float4* qy = (const float4*)(psy + b*NN + tid*8);
    const float4* qz = (const float4*)(psz + b*NN + tid*8);
    float4 a, c;
    a = qx[0]; c = qx[1];
    px2[0]=(f32x2_t){a.x,a.y}; px2[1]=(f32x2_t){a.z,a.w}; px2[2]=(f32x2_t){c.x,c.y}; px2[3]=(f32x2_t){c.z,c.w};
    a = qy[0]; c = qy[1];
    py2[0]=(f32x2_t){a.x,a.y}; py2[1]=(f32x2_t){a.z,a.w}; py2[2]=(f32x2_t){c.x,c.y}; py2[3]=(f32x2_t){c.z,c.w};
    a = qz[0]; c = qz[1];
    pz2[0]=(f32x2_t){a.x,a.y}; pz2[1]=(f32x2_t){a.z,a.w}; pz2[2]=(f32x2_t){c.x,c.y}; pz2[3]=(f32x2_t){c.z,c.w};
    const int4* qi = (const int4*)(iorig + b*NN + tid*8);
    int4 i0 = qi[0], i1 = qi[1];
    io[0]=i0.x; io[1]=i0.y; io[2]=i0.z; io[3]=i0.w;
    io[4]=i1.x; io[5]=i1.y; io[6]=i1.z; io[7]=i1.w;
  }
  #pragma unroll
  for (int q = 0; q < 4; q++) dmin2[q] = (f32x2_t){1e10f, 1e10f};
  // per-lane bbox over the lane's 8 Morton-consecutive points
  float llx, lhx, lly, lhy, llz, lhz;
  {
    llx = fminf(fminf(px2[0].x,px2[0].y), fminf(px2[1].x,px2[1].y));
    llx = fminf(llx, fminf(fminf(px2[2].x,px2[2].y), fminf(px2[3].x,px2[3].y)));
    lhx = fmaxf(fmaxf(px2[0].x,px2[0].y), fmaxf(px2[1].x,px2[1].y));
    lhx = fmaxf(lhx, fmaxf(fmaxf(px2[2].x,px2[2].y), fmaxf(px2[3].x,px2[3].y)));
    lly = fminf(fminf(py2[0].x,py2[0].y), fminf(py2[1].x,py2[1].y));
    lly = fminf(lly, fminf(fminf(py2[2].x,py2[2].y), fminf(py2[3].x,py2[3].y)));
    lhy = fmaxf(fmaxf(py2[0].x,py2[0].y), fmaxf(py2[1].x,py2[1].y));
    lhy = fmaxf(lhy, fmaxf(fmaxf(py2[2].x,py2[2].y), fmaxf(py2[3].x,py2[3].y)));
    llz = fminf(fminf(pz2[0].x,pz2[0].y), fminf(pz2[1].x,pz2[1].y));
    llz = fminf(llz, fminf(fminf(pz2[2].x,pz2[2].y), fminf(pz2[3].x,pz2[3].y)));
    lhz = fmaxf(fmaxf(pz2[0].x,pz2[0].y), fmaxf(pz2[1].x,pz2[1].y));
    lhz = fmaxf(lhz, fmaxf(fmaxf(pz2[2].x,pz2[2].y), fmaxf(pz2[3].x,pz2[3].y)));
  }
  __syncthreads();
  int far = 0;
  bool isf32 = (*flag != 0);
  float* outf = (float*)d_out; unsigned short* outh = (unsigned short*)d_out;
  int ln = tid & 63, w = tid >> 6;
  unsigned cached_lo = 0u, cached_hi = 0u;
  float lmax = 1e10f;                      // lane's max dmin over its 8 points
  int rot = 0;
  for (int s = 0; s < SS; s++){
    int rotn = rot + 1; if (rotn == 3) rotn = 0;
    float4 cf = *(const float4*)&sxyz4[(size_t)far*4];
    float cx = cf.x, cy = cf.y, cz = cf.z;
    if (tid == 0){
      fps_idx[b*SS + s] = far;
      size_t o = ((size_t)b*SS + s)*3;
      if (isf32){ outf[o]=cx; outf[o+1]=cy; outf[o+2]=cz; }
      else { outh[o]=f2bf(cx); outh[o+1]=f2bf(cy); outh[o+2]=f2bf(cz); }
    }
    if (tid == 64){ rk[rotn][0] = 0ull; rk[rotn][1] = 0ull; }  // slot quiescent since s-2
    float dxl = fmaxf(fmaxf(llx - cx, cx - lhx), 0.f);
    float dyl = fmaxf(fmaxf(lly - cy, cy - lhy), 0.f);
    float dzl = fmaxf(fmaxf(llz - cz, cz - lhz), 0.f);
    float d2l = (dxl*dxl + dyl*dyl + dzl*dzl) * 0.99999f;
    bool upd = (s == 0) || __any(d2l < lmax);
    if (upd){
      f32x2_t cx2 = (f32x2_t){cx, cx}, cy2 = (f32x2_t){cy, cy}, cz2 = (f32x2_t){cz, cz};
      bool ch = false;
      {
        #pragma clang fp contract(off)
        #pragma unroll
        for (int q = 0; q < 4; q++){
          f32x2_t dx = px2[q] - cx2, dy = py2[q] - cy2, dz = pz2[q] - cz2;
          f32x2_t t = dx*dx;
          t = t + dy*dy;
          t = t + dz*dz;
          ch = ch | (t.x < dmin2[q].x) | (t.y < dmin2[q].y);
          dmin2[q].x = fminf(dmin2[q].x, t.x);
          dmin2[q].y = fminf(dmin2[q].y, t.y);
        }
      }
      if (__any(ch)){
        float m0 = fmaxf(fmaxf(dmin2[0].x, dmin2[0].y), fmaxf(dmin2[1].x, dmin2[1].y));
        float m1 = fmaxf(fmaxf(dmin2[2].x, dmin2[2].y), fmaxf(dmin2[3].x, dmin2[3].y));
        float lm = fmaxf(m0, m1);
        lmax = lm;                         // refresh lane bound (free byproduct)
        lm = dpp_maxf<0x111>(lm); lm = dpp_maxf<0x112>(lm);
        lm = dpp_maxf<0x114>(lm); lm = dpp_maxf<0x118>(lm);
        lm = dpp_maxf<0x142>(lm); lm = dpp_maxf<0x143>(lm);
        float wmax = i2f(__builtin_amdgcn_readlane(f2i(lm), 63));
        unsigned cand = 0xFFFFFFFFu;
        #pragma unroll
        for (int q = 0; q < 4; q++){
          if (dmin2[q].x == wmax){ unsigned u = (unsigned)io[2*q];   cand = u < cand ? u : cand; }
          if (dmin2[q].y == wmax){ unsigned u = (unsigned)io[2*q+1]; cand = u < cand ? u : cand; }
        }
        cand = dpp_minu<0x111>(cand); cand = dpp_minu<0x112>(cand);
        cand = dpp_minu<0x114>(cand); cand = dpp_minu<0x118>(cand);
        cand = dpp_minu<0x142>(cand); cand = dpp_minu<0x143>(cand);
        unsigned cmin = (unsigned)__builtin_amdgcn_readlane((int)cand, 63);
        cached_hi = (unsigned)f2i(wmax);
        cached_lo = ~cmin;
      }
    }
    if (ln == 63)
      atomicMax(&rk[rot][w >> 3], (((unsigned long long)cached_hi) << 32) | cached_lo);
    __syncthreads();
    unsigned long long k0 = rk[rot][0], k1 = rk[rot][1];
    unsigned long long kk = (k1 > k0) ? k1 : k0;
    far = (int)(~(unsigned)kk);
    rot = rotn;
  }
}

// ---------------- kNN: radix-histogram selection, coalesced planar loads ----------------
__global__ __launch_bounds__(256) void knn_kernel(
    const float* psx, const float* psy, const float* psz, const int* ior,
    const float* xyzf, const int* fps_idx, int* knn){
  int cg = blockIdx.x;
  int b = cg >> 11;
  int tid = threadIdx.x;
  const float* xb = xyzf + (size_t)b*NN*3;
  __shared__ unsigned hist[4096];
  __shared__ unsigned long long cand[512];
  __shared__ unsigned psum[256];
  __shared__ unsigned exbase[64];
  __shared__ float scc[3];
  __shared__ int sB, sBase, sCl, sCc;
  __shared__ unsigned long long rmin[4];
  __shared__ unsigned long long swin;

  if (tid == 0){
    int f = fps_idx[cg];
    scc[0] = xb[f*3]; scc[1] = xb[f*3+1]; scc[2] = xb[f*3+2];
    sCl = 0; sCc = 0;
  }
  #pragma unroll
  for (int i = 0; i < 16; i++) hist[tid*16 + i] = 0;
  __syncthreads();
  float cx = scc[0], cy = scc[1], cz = scc[2];

  float dv[32]; int iv[32];
  const float4* qx = (const float4*)(psx + b*NN);
  const float4* qy = (const float4*)(psy + b*NN);
  const float4* qz = (const float4*)(psz + b*NN);
  const int4*   qi = (const int4*)(ior + b*NN);
  {
    #pragma clang fp contract(off)
    #pragma unroll
    for (int k = 0; k < 8; k++){
      float4 X = qx[k*256 + tid];
      float4 Y = qy[k*256 + tid];
      float4 Z = qz[k*256 + tid];
      int4   I = qi[k*256 + tid];
      float xs_[4] = {X.x, X.y, X.z, X.w};
      float ys_[4] = {Y.x, Y.y, Y.z, Y.w};
      float zs_[4] = {Z.x, Z.y, Z.z, Z.w};
      int   is_[4] = {I.x, I.y, I.z, I.w};
      #pragma unroll
      for (int r = 0; r < 4; r++){
        float dx = cx - xs_[r], dy = cy - ys_[r], dz = cz - zs_[r];
        dv[k*4 + r] = dx*dx + dy*dy + dz*dz;
        iv[k*4 + r] = is_[r];
      }
    }
  }
  #pragma unroll
  for (int t = 0; t < 32; t++)
    atomicAdd(&hist[((unsigned)f2i(dv[t])) >> 20], 1u);
  __syncthreads();
  unsigned lsum = 0;
  #pragma unroll
  for (int i = 0; i < 16; i++) lsum += hist[tid*16 + i];
  psum[tid] = lsum;
  __syncthreads();
  if (tid < 64){
    unsigned s4 = psum[tid*4] + psum[tid*4+1] + psum[tid*4+2] + psum[tid*4+3];
    unsigned inc = s4;
    #pragma unroll
    for (int off = 1; off < 64; off <<= 1){
      unsigned o = __shfl_up(inc, off);
      if (tid >= off) inc += o;
    }
    exbase[tid] = inc - s4;
  }
  __syncthreads();
  {
    int g4 = tid >> 2;
    unsigned ex = exbase[g4];
    for (int j = g4*4; j < tid; j++) ex += psum[j];
    unsigned run = ex;
    #pragma unroll
    for (int i = 0; i < 16; i++){
      unsigned c = hist[tid*16 + i];
      if (run < 32u && run + c >= 32u){ sB = tid*16 + i; sBase = (int)run; }
      run += c;
    }
  }
  __syncthreads();
  int Bbin = sB, base = sBase;
  int out = cg << 5;
  #pragma unroll
  for (int t = 0; t < 32; t++){
    unsigned bits = (unsigned)f2i(dv[t]);
    unsigned hb = bits >> 20;
    int idx = iv[t];
    if ((int)hb < Bbin){
      int sl = atomicAdd(&sCl, 1);
      knn[out + sl] = idx;
    } else if ((int)hb == Bbin){
      int c = atomicAdd(&sCc, 1);
      if (c < 512) cand[c] = (((unsigned long long)bits) << 32) | (unsigned)idx;
    }
  }
  __syncthreads();
  int cc = sCc; if (cc > 512) cc = 512;
  int r = 32 - base;
  for (int round = 0; round < r; round++){
    unsigned long long lm = ~0ull;
    for (int i = tid; i < cc; i += 256){
      unsigned long long v = cand[i];
      if (v < lm) lm = v;
    }
    #pragma unroll
    for (int off = 1; off < 64; off <<= 1){
      unsigned long long o = __shfl_xor(lm, off);
      if (o < lm) lm = o;
    }
    if ((tid & 63) == 0) rmin[tid >> 6] = lm;
    __syncthreads();
    if (tid == 0){
      unsigned long long m = rmin[0];
      #pragma unroll
      for (int q = 1; q < 4; q++) if (rmin[q] < m) m = rmin[q];
      swin = m;
      knn[out + base + round] = (int)(unsigned)m;
    }
    __syncthreads();
    unsigned long long m = swin;
    for (int i = tid; i < cc; i += 256)
      if (cand[i] == m) cand[i] = ~0ull;
    __syncthreads();
  }
}

// ---------------- materialized MLP passes (BN finalize folded in) ----------------
__device__ __forceinline__ bf16x8_t bfrag(const unsigned short* wp, int f, int lane){
  return *(const bf16x8_t*)(wp + ((size_t)f << 9) + (lane << 3));
}
__device__ __forceinline__ bf16x8_t bn_frag(bf16x8_t v, const float* a, const float* c, int kbase){
  float4 a0 = *(const float4*)(a + kbase); float4 a1 = *(const float4*)(a + kbase + 4);
  float4 c0 = *(const float4*)(c + kbase); float4 c1 = *(const float4*)(c + kbase + 4);
  float av[8] = {a0.x,a0.y,a0.z,a0.w,a1.x,a1.y,a1.z,a1.w};
  float cv[8] = {c0.x,c0.y,c0.z,c0.w,c1.x,c1.y,c1.z,c1.w};
  bf16x8_t r;
  #pragma unroll
  for (int j = 0; j < 8; j++)
    r[j] = (short)f2bf(fmaxf(bf2f((unsigned short)v[j])*av[j] + cv[j], 0.f));
  return r;
}

template<int TILES>
__global__ __launch_bounds__(256) void passA(
    const float* __restrict__ xyzf, const unsigned short* __restrict__ ptsb,
    const int* __restrict__ fpsi, const int* __restrict__ knn,
    const unsigned short* __restrict__ w0p,
    unsigned short* __restrict__ y0g, float* osum, float* osq)
{
  __shared__ unsigned short xb0[64*104];
  __shared__ unsigned short st[64*72];
  __shared__ float sacc[128];
  int tid = threadIdx.x, lane = tid & 63, w = tid >> 6;
  int l15 = lane & 15, quad = lane >> 4;
  float ssum[4], ssq[4];
  #pragma unroll
  for (int c = 0; c < 4; c++){ ssum[c] = 0.f; ssq[c] = 0.f; }
  if (tid < 128) sacc[tid] = 0.f;
  __syncthreads();

  for (int t = 0; t < TILES; t++){
    int row0 = (blockIdx.x * TILES + t) * 64;
    {
      int r = tid >> 2, p = tid & 3;
      int g = row0 + r;
      int bq = g >> 16, s = (g >> 5) & 2047;
      int n = knn[g];
      const bf16x8_t* pr = (const bf16x8_t*)(ptsb + (((size_t)bq*NN + n) << 6));
      *(bf16x8_t*)&xb0[r*104 + p*16]     = pr[p*2];
      *(bf16x8_t*)&xb0[r*104 + p*16 + 8] = pr[p*2 + 1];
      if (p == 3){
        const float* xbp = xyzf + (size_t)bq*NN*3;
        int f = fpsi[(bq << 11) + s];
        float dx = xbp[n*3]   - xbp[f*3];
        float dy = xbp[n*3+1] - xbp[f*3+1];
        float dz = xbp[n*3+2] - xbp[f*3+2];
        bf16x8_t v = {(short)f2bf(dx), (short)f2bf(dy), (short)f2bf(dz), 0,0,0,0,0};
        bf16x8_t z = {0,0,0,0,0,0,0,0};
        *(bf16x8_t*)&xb0[r*104 + 64] = v;
        *(bf16x8_t*)&xb0[r*104 + 72] = z;
        *(bf16x8_t*)&xb0[r*104 + 80] = z;
        *(bf16x8_t*)&xb0[r*104 + 88] = z;
      }
    }
    bf16x8_t a0[3];
    #pragma unroll
    for (int ks = 0; ks < 3; ks++)
      a0[ks] = *(const bf16x8_t*)&xb0[(w*16 + l15)*104 + ks*32 + quad*8];
    #pragma unroll
    for (int ct = 0; ct < 4; ct++){
      f32x4_t a = {0.f,0.f,0.f,0.f};
      #pragma unroll
      for (int ks = 0; ks < 3; ks++)
        a = __builtin_amdgcn_mfma_f32_16x16x32_bf16(a0[ks], bfrag(w0p, ct*3+ks, lane), a, 0, 0, 0);
      #pragma unroll
      for (int r = 0; r < 4; r++){
        float v = a[r]; ssum[ct] += v; ssq[ct] += v*v;
        st[(w*16 + quad*4 + r)*72 + ct*16 + l15] = f2bf(v);
      }
    }
    __syncthreads();
    #pragma unroll
    for (int p = 0; p < 2; p++){
      int idx = p*2048 + tid*8; int r = idx >> 6; int c = idx & 63;
      *(bf16x8_t*)(y0g + (size_t)row0*64 + idx) = *(const bf16x8_t*)&st[r*72 + c];
    }
    __syncthreads();
  }
  #pragma unroll
  for (int c = 0; c < 4; c++){
    ssum[c] += __shfl_xor(ssum[c], 16); ssum[c] += __shfl_xor(ssum[c], 32);
    ssq [c] += __shfl_xor(ssq [c], 16); ssq [c] += __shfl_xor(ssq [c], 32);
  }
  if (quad == 0){
    #pragma unroll
    for (int c = 0; c < 4; c++){
      atomicAdd(&sacc[c*16 + l15], ssum[c]);
      atomicAdd(&sacc[64 + c*16 + l15], ssq[c]);
    }
  }
  __syncthreads();
  if (tid < 64){
    atomicAdd(&osum[tid], sacc[tid]);
    atomicAdd(&osq [tid], sacc[64 + tid]);
  }
}

template<int TILES>
__global__ __launch_bounds__(256) void passB(
    const unsigned short* __restrict__ y0g, const unsigned short* __restrict__ w1p,
    const float* __restrict__ stats, const float* __restrict__ gbf,
    unsigned short* __restrict__ y1g, float* osum, float* osq)
{
  __shared__ unsigned short st[64*136];
  __shared__ float sacc[256];
  __shared__ __align__(16) float sbn[128];
  int tid = threadIdx.x, lane = tid & 63, w = tid >> 6;
  int l15 = lane & 15, quad = lane >> 4;
  float ssum[8], ssq[8];
  #pragma unroll
  for (int c = 0; c < 8; c++){ ssum[c] = 0.f; ssq[c] = 0.f; }
  sacc[tid] = 0.f;
  if (tid < 64){
    const float invM = 1.0f/262144.0f;
    float mu = stats[tid]*invM;
    float var = fmaxf(stats[64+tid]*invM - mu*mu, 0.f);
    float inv = 1.0f/sqrtf(var + 1e-5f);
    float av = gbf[tid]*inv;
    sbn[tid] = av; sbn[64+tid] = gbf[64+tid] - mu*av;
  }
  __syncthreads();

  for (int t = 0; t < TILES; t++){
    int row0 = (blockIdx.x * TILES + t) * 64;
    int row = row0 + w*16 + l15;
    bf16x8_t a1[2];
    #pragma unroll
    for (int ks = 0; ks < 2; ks++){
      bf16x8_t v = *(const bf16x8_t*)(y0g + (size_t)row*64 + ks*32 + quad*8);
      a1[ks] = bn_frag(v, sbn, sbn + 64, ks*32 + quad*8);
    }
    #pragma unroll
    for (int ct = 0; ct < 8; ct++){
      f32x4_t a = {0.f,0.f,0.f,0.f};
      #pragma unroll
      for (int ks = 0; ks < 2; ks++)
        a = __builtin_amdgcn_mfma_f32_16x16x32_bf16(a1[ks], bfrag(w1p, ct*2+ks, lane), a, 0, 0, 0);
      #pragma unroll
      for (int r = 0; r < 4; r++){
        float v = a[r]; ssum[ct] += v; ssq[ct] += v*v;
        st[(w*16 + quad*4 + r)*136 + ct*16 + l15] = f2bf(v);
      }
    }
    __syncthreads();
    #pragma unroll
    for (int p = 0; p < 4; p++){
      int idx = p*2048 + tid*8; int r = idx >> 7; int c = idx & 127;
      *(bf16x8_t*)(y1g + (size_t)row0*128 + idx) = *(const bf16x8_t*)&st[r*136 + c];
    }
    __syncthreads();
  }
  #pragma unroll
  for (int c = 0; c < 8; c++){
    ssum[c] += __shfl_xor(ssum[c], 16); ssum[c] += __shfl_xor(ssum[c], 32);
    ssq [c] += __shfl_xor(ssq [c], 16); ssq [c] += __shfl_xor(ssq [c], 32);
  }
  if (quad == 0){
    #pragma unroll
    for (int c = 0; c < 8; c++){
      atomicAdd(&sacc[c*16 + l15], ssum[c]);
      atomicAdd(&sacc[128 + c*16 + l15], ssq[c]);
    }
  }
  __syncthreads();
  if (tid < 128){
    atomicAdd(&osum[tid], sacc[tid]);
    atomicAdd(&osq [tid], sacc[128 + tid]);
  }
}

template<int TILES>
__global__ __launch_bounds__(256) void passC(
    const unsigned short* __restrict__ y1g, const unsigned short* __restrict__ w2p,
    const float* __restrict__ stats, const float* __restrict__ gbf,
    float* osum, float* osq)
{
  __shared__ float sacc[512];
  __shared__ __align__(16) float sbn[256];
  int tid = threadIdx.x, lane = tid & 63, w = tid >> 6;
  int l15 = lane & 15, quad = lane >> 4;
  float ssum[16], ssq[16];
  #pragma unroll
  for (int c = 0; c < 16; c++){ ssum[c] = 0.f; ssq[c] = 0.f; }
  sacc[tid] = 0.f; sacc[tid + 256] = 0.f;
  if (tid < 128){
    const float invM = 1.0f/262144.0f;
    float mu = stats[128+tid]*invM;
    float var = fmaxf(stats[256+tid]*invM - mu*mu, 0.f);
    float inv = 1.0f/sqrtf(var + 1e-5f);
    float av = gbf[128+tid]*inv;
    sbn[tid] = av; sbn[128+tid] = gbf[256+tid] - mu*av;
  }
  __syncthreads();

  for (int t = 0; t < TILES; t++){
    int row0 = (blockIdx.x * TILES + t) * 64;
    int row = row0 + w*16 + l15;
    bf16x8_t a2[4];
    #pragma unroll
    for (int ks = 0; ks < 4; ks++){
      bf16x8_t v = *(const bf16x8_t*)(y1g + (size_t)row*128 + ks*32 + quad*8);
      a2[ks] = bn_frag(v, sbn, sbn + 128, ks*32 + quad*8);
    }
    #pragma unroll
    for (int ct = 0; ct < 16; ct++){
      f32x4_t a = {0.f,0.f,0.f,0.f};
      #pragma unroll
      for (int ks = 0; ks < 4; ks++)
        a = __builtin_amdgcn_mfma_f32_16x16x32_bf16(a2[ks], bfrag(w2p, ct*4+ks, lane), a, 0, 0, 0);
      #pragma unroll
      for (int r = 0; r < 4; r++){ float v = a[r]; ssum[ct] += v; ssq[ct] += v*v; }
    }
  }
  #pragma unroll
  for (int c = 0; c < 16; c++){
    ssum[c] += __shfl_xor(ssum[c], 16); ssum[c] += __shfl_xor(ssum[c], 32);
    ssq [c] += __shfl_xor(ssq [c], 16); ssq [c] += __shfl_xor(ssq [c], 32);
  }
  if (quad == 0){
    #pragma unroll
    for (int c = 0; c < 16; c++){
      atomicAdd(&sacc[c*16 + l15], ssum[c]);
      atomicAdd(&sacc[256 + c*16 + l15], ssq[c]);
    }
  }
  __syncthreads();
  if (tid < 256){
    atomicAdd(&osum[tid], sacc[tid]);
    atomicAdd(&osq [tid], sacc[256 + tid]);
  }
}

__global__ __launch_bounds__(256) void passD(
    const unsigned short* __restrict__ y1g, const unsigned short* __restrict__ w2p,
    const float* __restrict__ stats, const float* __restrict__ gbf,
    void* d_out, const int* __restrict__ flag)
{
  __shared__ float smax[1024];
  __shared__ __align__(16) float sbn[768];  // a1[128] c1[128] a2[256] c2[256]
  int tid = threadIdx.x, lane = tid & 63, w = tid >> 6;
  int l15 = lane & 15, quad = lane >> 4;
  {
    const float invM = 1.0f/262144.0f;
    if (tid < 128){
      float mu = stats[128+tid]*invM;
      float var = fmaxf(stats[256+tid]*invM - mu*mu, 0.f);
      float inv = 1.0f/sqrtf(var + 1e-5f);
      float av = gbf[128+tid]*inv;
      sbn[tid] = av; sbn[128+tid] = gbf[256+tid] - mu*av;
    }
    float mu2 = stats[384+tid]*invM;
    float var2 = fmaxf(stats[640+tid]*invM - mu2*mu2, 0.f);
    float inv2 = 1.0f/sqrtf(var2 + 1e-5f);
    float av2 = gbf[384+tid]*inv2;
    sbn[256+tid] = av2; sbn[512+tid] = gbf[640+tid] - mu2*av2;
  }
  __syncthreads();
  int row0 = blockIdx.x * 64;
  int row = row0 + w*16 + l15;
  bf16x8_t a2[4];
  #pragma unroll
  for (int ks = 0; ks < 4; ks++){
    bf16x8_t v = *(const bf16x8_t*)(y1g + (size_t)row*128 + ks*32 + quad*8);
    a2[ks] = bn_frag(v, sbn, sbn + 128, ks*32 + quad*8);
  }
  #pragma unroll
  for (int ct = 0; ct < 16; ct++){
    f32x4_t a = {0.f,0.f,0.f,0.f};
    #pragma unroll
    for (int ks = 0; ks < 4; ks++)
      a = __builtin_amdgcn_mfma_f32_16x16x32_bf16(a2[ks], bfrag(w2p, ct*4+ks, lane), a, 0, 0, 0);
    int o = ct*16 + l15;
    float ga = sbn[256 + o], gc = sbn[512 + o];
    float m = fmaxf(fmaxf(a[0]*ga + gc, a[1]*ga + gc), fmaxf(a[2]*ga + gc, a[3]*ga + gc));
    m = fmaxf(m, __shfl_xor(m, 16));
    m = fmaxf(m, __shfl_xor(m, 32));
    if (quad == 0) smax[w*256 + o] = m;
  }
  __syncthreads();
  float v0 = fmaxf(fmaxf(smax[tid], smax[256 + tid]), 0.f);
  float v1 = fmaxf(fmaxf(smax[512 + tid], smax[768 + tid]), 0.f);
  int cg = blockIdx.x * 2;
  bool isf32 = (*flag != 0);
  int b0 = cg >> 11, s0 = cg & 2047;
  int b1 = (cg+1) >> 11, s1 = (cg+1) & 2047;
  size_t o0 = (size_t)BB*SS*3 + (((size_t)(b0*256 + tid)) << 11) + s0;
  size_t o1 = (size_t)BB*SS*3 + (((size_t)(b1*256 + tid)) << 11) + s1;
  if (isf32){ ((float*)d_out)[o0] = v0; ((float*)d_out)[o1] = v1; }
  else { ((unsigned short*)d_out)[o0] = f2bf(v0); ((unsigned short*)d_out)[o1] = f2bf(v1); }
}

// ---------------- workspace layout (bytes) ----------------
#define OFF_FLAG   0u
#define OFF_FPS    256u
#define OFF_KNN    33024u
#define OFF_STATS  1081600u
#define OFF_XYZF   1088768u
#define OFF_GB     1481984u
#define OFF_W0P    1485568u
#define OFF_W1P    1497856u
#define OFF_W2P    1514240u
#define OFF_PTSB   1579776u
#define OFF_Y0     5774336u
#define OFF_Y1     39328768u
#define OFF_PSX    (OFF_Y1)
#define OFF_PSY    (OFF_Y1 + 131072u)
#define OFF_PSZ    (OFF_Y1 + 262144u)
#define OFF_IOR    (OFF_Y1 + 393216u)

extern "C" void kernel_launch(void* const* d_in, const int* in_sizes, int n_in,
                              void* d_out, int out_size, void* d_ws, size_t ws_size,
                              hipStream_t stream){
  char* ws = (char*)d_ws;
  int*   flag  = (int*)(ws + OFF_FLAG);
  int*   fpsi  = (int*)(ws + OFF_FPS);
  int*   knn   = (int*)(ws + OFF_KNN);
  float* stats = (float*)(ws + OFF_STATS);
  float* xyzf  = (float*)(ws + OFF_XYZF);
  float* gbf   = (float*)(ws + OFF_GB);
  unsigned short* w0p = (unsigned short*)(ws + OFF_W0P);
  unsigned short* w1p = (unsigned short*)(ws + OFF_W1P);
  unsigned short* w2p = (unsigned short*)(ws + OFF_W2P);
  unsigned short* ptsb = (unsigned short*)(ws + OFF_PTSB);
  unsigned short* y0g = (unsigned short*)(ws + OFF_Y0);
  unsigned short* y1g = (unsigned short*)(ws + OFF_Y1);
  float* psx = (float*)(ws + OFF_PSX);
  float* psy = (float*)(ws + OFF_PSY);
  float* psz = (float*)(ws + OFF_PSZ);
  int*   ior = (int*)(ws + OFF_IOR);

  detect_kernel<<<1, 256, 0, stream>>>(d_in[1], flag);
  prep_kernel<<<572, 256, 0, stream>>>(d_in[0], d_in[2], d_in[5], d_in[8],
                                       d_in[3], d_in[4], d_in[6], d_in[7], d_in[9], d_in[10],
                                       xyzf, w0p, w1p, w2p, gbf, stats, flag);

  morton_sort<<<BB, 1024, 0, stream>>>(xyzf, psx, psy, psz, ior);
  fps_kernel<<<4 + 128, 1024, 0, stream>>>(xyzf, psx, psy, psz, ior, fpsi, d_out, flag,
                                           d_in[1], ptsb);
  knn_kernel<<<BB*SS, 256, 0, stream>>>(psx, psy, psz, ior, xyzf, fpsi, knn);

  passA<4><<<1024, 256, 0, stream>>>(xyzf, ptsb, fpsi, knn, w0p, y0g, stats + 0, stats + 64);
  passB<4><<<1024, 256, 0, stream>>>(y0g, w1p, stats, gbf, y1g, stats + 128, stats + 256);
  passC<4><<<1024, 256, 0, stream>>>(y1g, w2p, stats, gbf, stats + 384, stats + 640);
  passD<<<4096, 256, 0, stream>>>(y1g, w2p, stats, gbf, d_out, flag);
  (void)in_sizes; (void)n_in; (void)out_size; (void)ws_size;
}

// Round 9
// 1789.310 us; speedup vs baseline: 1.1207x; 1.0013x over previous
//
#include <hip/hip_runtime.h>

#define BB 4
#define NN 8192
#define CC 64
#define SS 2048
#define KK 32
#define MROWS (BB*SS*KK)   // 262144

typedef __attribute__((ext_vector_type(8))) short bf16x8_t;
typedef __attribute__((ext_vector_type(8))) unsigned short u16x8_t;
typedef __attribute__((ext_vector_type(4))) float f32x4_t;
typedef __attribute__((ext_vector_type(2))) float f32x2_t;

__device__ __forceinline__ float bf2f(unsigned short u){
  union { unsigned int i; float f; } v; v.i = ((unsigned int)u) << 16; return v.f;
}
__device__ __forceinline__ unsigned short f2bf(float f){
  union { float f; unsigned int i; } v; v.f = f;
  unsigned int u = v.i;
  unsigned int r = (u + 0x7FFFu + ((u >> 16) & 1u)) >> 16;
  return (unsigned short)r;
}
__device__ __forceinline__ float i2f(int i){ union { int i; float f; } v; v.i = i; return v.f; }
__device__ __forceinline__ int f2i(float f){ union { float f; int i; } v; v.f = f; return v.i; }

// ---------------- dtype detection ----------------
__global__ void detect_kernel(const void* pts, int* flag){
  __shared__ int cnt;
  if (threadIdx.x == 0) cnt = 0;
  __syncthreads();
  unsigned short u = ((const unsigned short*)pts)[threadIdx.x];
  int e = (u >> 7) & 0xFF;
  if (e != 0 && (e < 112 || e > 143)) atomicAdd(&cnt, 1);
  __syncthreads();
  if (threadIdx.x == 0) *flag = (cnt > 32) ? 1 : 0;
}

// ---------------- merged prep+morton (one dispatch, 1024-thr blocks) ----------------
// R9: morton absorbs the xyz dtype conversion (reads raw input, writes xyzf
// as a side product), removing the prep->morton dependency; the remaining
// prep work (gb/stats + weight packs, flat elementwise) rides in the same
// dispatch as blocks 4..50. Two launches -> one.
__device__ __forceinline__ void pack_dev(const void* src, unsigned short* dst,
    int CTS, int KSTEPS, int IN, int remap, int idx, bool isf){
  int total = CTS*KSTEPS*512;
  if (idx >= total) return;
  int f = idx >> 9, lane = (idx >> 3) & 63, j = idx & 7;
  int ct = f / KSTEPS, ks = f % KSTEPS;
  int n = ct*16 + (lane & 15);
  int k = ks*32 + (lane >> 4)*8 + j;
  int ksrc;
  if (remap){ ksrc = (k < 64) ? (k + 3) : (k < 67 ? k - 64 : -1); }
  else      { ksrc = (k < IN) ? k : -1; }
  float v = 0.f;
  if (ksrc >= 0){
    size_t si = (size_t)n*IN + ksrc;
    v = isf ? ((const float*)src)[si] : bf2f(((const unsigned short*)src)[si]);
  }
  dst[idx] = f2bf(v);
}

__device__ __forceinline__ unsigned mspread(unsigned v){
  v = (v | (v << 16)) & 0x030000FFu;
  v = (v | (v <<  8)) & 0x0300F00Fu;
  v = (v | (v <<  4)) & 0x030C30C3u;
  v = (v | (v <<  2)) & 0x09249249u;
  return v;
}

__global__ __launch_bounds__(1024) void prep_morton(
    const void* xyz_in,
    const void* w0_in, const void* w1_in, const void* w2_in,
    const void* g0, const void* b0, const void* g1, const void* b1,
    const void* g2, const void* b2,
    float* xyzf, float* psx, float* psy, float* psz, int* iorig,
    unsigned short* w0p, unsigned short* w1p, unsigned short* w2p,
    float* gbf, float* stats, const int* flag)
{
  int blk = blockIdx.x, tid = threadIdx.x;
  bool isf = (*flag != 0);
  if (blk >= 4){
    int i1024 = tid;  // flat idx within branch
    if (blk == 4){
      int i = i1024;
      if (i < 896){
        const void* src; int off;
        if      (i < 64)  { src = g0; off = i; }
        else if (i < 128) { src = b0; off = i - 64; }
        else if (i < 256) { src = g1; off = i - 128; }
        else if (i < 384) { src = b1; off = i - 256; }
        else if (i < 640) { src = g2; off = i - 384; }
        else              { src = b2; off = i - 640; }
        gbf[i] = isf ? ((const float*)src)[off] : bf2f(((const unsigned short*)src)[off]);
        stats[i] = 0.f;
      }
    } else if (blk < 11){
      pack_dev(w0_in, w0p, 4, 3, 67, 1, (blk-5)*1024 + i1024, isf);
    } else if (blk < 19){
      pack_dev(w1_in, w1p, 8, 2, 64, 0, (blk-11)*1024 + i1024, isf);
    } else {
      pack_dev(w2_in, w2p, 16, 4, 128, 0, (blk-19)*1024 + i1024, isf);
    }
    return;
  }
  // ---- morton branch: batch b = blk; integrated dtype conversion ----
  int b = blk;
  int lane = tid & 63, wid = tid >> 6;
  __shared__ unsigned curs[NN];     // 32 KiB: histogram, then exclusive-prefix cursors
  __shared__ float rbb[96];
  __shared__ unsigned wsum[16];
  float v24[24];
  if (isf){
    const float4* p4 = (const float4*)((const float*)xyz_in + (size_t)b*NN*3 + (size_t)tid*24);
    #pragma unroll
    for (int q = 0; q < 6; q++){
      float4 t = p4[q];
      v24[q*4] = t.x; v24[q*4+1] = t.y; v24[q*4+2] = t.z; v24[q*4+3] = t.w;
    }
  } else {
    const u16x8_t* p8 = (const u16x8_t*)((const unsigned short*)xyz_in + (size_t)b*NN*3 + (size_t)tid*24);
    #pragma unroll
    for (int q = 0; q < 3; q++){
      u16x8_t t = p8[q];
      #pragma unroll
      for (int j = 0; j < 8; j++) v24[q*8 + j] = bf2f((unsigned short)t[j]);
    }
  }
  // side product: converted xyz for downstream consumers
  {
    float4* xo = (float4*)(xyzf + (size_t)b*NN*3 + (size_t)tid*24);
    #pragma unroll
    for (int q = 0; q < 6; q++){
      float4 t; t.x = v24[q*4]; t.y = v24[q*4+1]; t.z = v24[q*4+2]; t.w = v24[q*4+3];
      xo[q] = t;
    }
  }
  float x[8], y[8], z[8];
  #pragma unroll
  for (int j = 0; j < 8; j++){ x[j] = v24[j*3]; y[j] = v24[j*3+1]; z[j] = v24[j*3+2]; }
  float lx=x[0],hx=x[0],ly=y[0],hy=y[0],lz=z[0],hz=z[0];
  #pragma unroll
  for (int j = 1; j < 8; j++){
    lx=fminf(lx,x[j]); hx=fmaxf(hx,x[j]);
    ly=fminf(ly,y[j]); hy=fmaxf(hy,y[j]);
    lz=fminf(lz,z[j]); hz=fmaxf(hz,z[j]);
  }
  #pragma unroll
  for (int off = 1; off < 64; off <<= 1){
    lx=fminf(lx,__shfl_xor(lx,off)); hx=fmaxf(hx,__shfl_xor(hx,off));
    ly=fminf(ly,__shfl_xor(ly,off)); hy=fmaxf(hy,__shfl_xor(hy,off));
    lz=fminf(lz,__shfl_xor(lz,off)); hz=fmaxf(hz,__shfl_xor(hz,off));
  }
  if (lane == 0){
    rbb[wid]=lx; rbb[16+wid]=hx; rbb[32+wid]=ly; rbb[48+wid]=hy; rbb[64+wid]=lz; rbb[80+wid]=hz;
  }
  for (int i = tid; i < NN; i += 1024) curs[i] = 0;
  __syncthreads();
  #pragma unroll
  for (int i = 0; i < 16; i++){
    lx=fminf(lx,rbb[i]); hx=fmaxf(hx,rbb[16+i]);
    ly=fminf(ly,rbb[32+i]); hy=fmaxf(hy,rbb[48+i]);
    lz=fminf(lz,rbb[64+i]); hz=fmaxf(hz,rbb[80+i]);
  }
  float sx = 1023.0f/fmaxf(hx-lx,1e-20f);
  float sy = 1023.0f/fmaxf(hy-ly,1e-20f);
  float sz = 1023.0f/fmaxf(hz-lz,1e-20f);
  unsigned bkt[8];
  #pragma unroll
  for (int j = 0; j < 8; j++){
    int qx = (int)((x[j]-lx)*sx); qx = qx < 0 ? 0 : (qx > 1023 ? 1023 : qx);
    int qy = (int)((y[j]-ly)*sy); qy = qy < 0 ? 0 : (qy > 1023 ? 1023 : qy);
    int qz = (int)((z[j]-lz)*sz); qz = qz < 0 ? 0 : (qz > 1023 ? 1023 : qz);
    unsigned code = mspread((unsigned)qx) | (mspread((unsigned)qy) << 1) | (mspread((unsigned)qz) << 2);
    bkt[j] = code >> 17;            // top 13 of 30 bits -> 8192 buckets
    atomicAdd(&curs[bkt[j]], 1u);
  }
  __syncthreads();
  // hierarchical exclusive scan of curs[8192]
  unsigned v[8]; unsigned s = 0;
  #pragma unroll
  for (int j = 0; j < 8; j++){ v[j] = curs[tid*8 + j]; s += v[j]; }
  unsigned inc = s;
  #pragma unroll
  for (int off = 1; off < 64; off <<= 1){
    unsigned o = __shfl_up(inc, off);
    if (lane >= off) inc += o;
  }
  if (lane == 63) wsum[wid] = inc;
  __syncthreads();
  if (tid == 0){
    unsigned r = 0;
    #pragma unroll
    for (int i = 0; i < 16; i++){ unsigned t = wsum[i]; wsum[i] = r; r += t; }
  }
  __syncthreads();
  unsigned run = wsum[wid] + inc - s;   // exclusive prefix of this thread's 8-chunk
  #pragma unroll
  for (int j = 0; j < 8; j++){ curs[tid*8 + j] = run; run += v[j]; }
  __syncthreads();
  // scatter
  #pragma unroll
  for (int j = 0; j < 8; j++){
    unsigned pos = atomicAdd(&curs[bkt[j]], 1u);
    psx[b*NN + pos] = x[j];
    psy[b*NN + pos] = y[j];
    psz[b*NN + pos] = z[j];
    iorig[b*NN + pos] = tid*8 + j;
  }
}

// ---------------- DPP helpers ----------------
template<int C>
__device__ __forceinline__ float dpp_maxf(float v){
  int t = __builtin_amdgcn_update_dpp(0, f2i(v), C, 0xF, 0xF, true);
  return fmaxf(v, i2f(t));
}
template<int C>
__device__ __forceinline__ unsigned dpp_minu(unsigned v){
  unsigned t = (unsigned)__builtin_amdgcn_update_dpp(-1, (int)v, C, 0xF, 0xF, false);
  return v < t ? v : t;
}

// ---------------- FPS (R6 body, proven) + co-scheduled pts transpose ----------------
// Blocks 0-3: FPS, one per batch. Blocks 4-131: points transpose (only passA
// consumes it) on CUs idle during the 4-CU FPS phase.
__global__ __launch_bounds__(1024, 1) void fps_kernel(const float* xyzf,
    const float* psx, const float* psy, const float* psz, const int* iorig,
    int* fps_idx, void* d_out, const int* flag,
    const void* pts_in, unsigned short* ptsb){
  int tid = threadIdx.x;
  __shared__ float sxyz4[NN*4];            // 128 KiB, [NN][4] padded (fps) / tile (transpose)
  __shared__ unsigned long long rk[3][2];
  if (blockIdx.x >= 4){
    // ---- pts transpose branch: 128 blocks x 1024 thr; 64ch x 256n tile ----
    int blk = blockIdx.x - 4;
    int b = blk >> 5, n0 = (blk & 31) * 256;
    bool isf = (*flag != 0);
    float (*tile)[257] = (float(*)[257])sxyz4;   // 64*257*4B = 65.8KB < 128KB
    #pragma unroll
    for (int k = 0; k < 16; k++){
      int idx = k*1024 + tid; int c = idx >> 8; int ni = idx & 255;
      size_t src = ((size_t)b*CC + c)*NN + n0 + ni;
      tile[c][ni] = isf ? ((const float*)pts_in)[src] : bf2f(((const unsigned short*)pts_in)[src]);
    }
    __syncthreads();
    #pragma unroll
    for (int k = 0; k < 16; k++){
      int idx = k*1024 + tid; int ni = idx >> 6; int c = idx & 63;
      ptsb[((size_t)b*NN + n0 + ni)*CC + c] = f2bf(tile[c][ni]);
    }
    return;
  }
  int b = blockIdx.x;
  const float* xb = xyzf + (size_t)b*NN*3;
  for (int i = tid; i < NN; i += 1024){
    const float* p = xb + (size_t)i*3;
    float4 v; v.x = p[0]; v.y = p[1]; v.z = p[2]; v.w = 0.f;
    *(float4*)&sxyz4[(size_t)i*4] = v;
  }
  if (tid < 6) ((unsigned long long*)rk)[tid] = 0ull;
  f32x2_t px2[4], py2[4], pz2[4], dmin2[4];
  int io[8];
  {
    const float4* qx = (const float4*)(psx + b*NN + tid*8);
    const float4* qy = (const float4*)(psy + b*NN + tid*8);
    const float4* qz = (const float4*)(psz + b*NN + tid*8);
    float4 a, c;
    a = qx[0]; c = qx[1];
    px2[0]=(f32x2_t){a.x,a.y}; px2[1]=(f32x2_t){a.z,a.w}; px2[2]=(f32x2_t){c.x,c.y}; px2[3]=(f32x2_t){c.z,c.w};
    a = qy[0]; c = qy[1];
    py2[0]=(f32x2_t){a.x,a.y}; py2[1]=(f32x2_t){a.z,a.w}; py2[2]=(f32x2_t){c.x,c.y}; py2[3]=(f32x2_t){c.z,c.w};
    a = qz[0]; c = qz[1];
    pz2[0]=(f32x2_t){a.x,a.y}; pz2[1]=(f32x2_t){a.z,a.w}; pz2[2]=(f32x2_t){c.x,c.y}; pz2[3]=(f32x2_t){c.z,c.w};
    const int4* qi = (const int4*)(iorig + b*NN + tid*8);
    int4 i0 = qi[0], i1 = qi[1];
    io[0]=i0.x; io[1]=i0.y; io[2]=i0.z; io[3]=i0.w;
    io[4]=i1.x; io[5]=i1.y; io[6]=i1.z; io[7]=i1.w;
  }
  #pragma unroll
  for (int q = 0; q < 4; q++) dmin2[q] = (f32x2_t){1e10f, 1e10f};
  // per-lane bbox over the lane's 8 Morton-consecutive points
  float llx, lhx, lly, lhy, llz, lhz;
  {
    llx = fminf(fminf(px2[0].x,px2[0].y), fminf(px2[1].x,px2[1].y));
    llx = fminf(llx, fminf(fminf(px2[2].x,px2[2].y), fminf(px2[3].x,px2[3].y)));
    lhx = fmaxf(fmaxf(px2[0].x,px2[0].y), fmaxf(px2[1].x,px2[1].y));
    lhx = fmaxf(lhx, fmaxf(fmaxf(px2[2].x,px2[2].y), fmaxf(px2[3].x,px2[3].y)));
    lly = fminf(fminf(py2[0].x,py2[0].y), fminf(py2[1].x,py2[1].y));
    lly = fminf(lly, fminf(fminf(py2[2].x,py2[2].y), fminf(py2[3].x,py2[3].y)));
    lhy = fmaxf(fmaxf(py2[0].x,py2[0].y), fmaxf(py2[1].x,py2[1].y));
    lhy = fmaxf(lhy, fmaxf(fmaxf(py2[2].x,py2[2].y), fmaxf(py2[3].x,py2[3].y)));
    llz = fminf(fminf(pz2[0].x,pz2[0].y), fminf(pz2[1].x,pz2[1].y));
    llz = fminf(llz, fminf(fminf(pz2[2].x,pz2[2].y), fminf(pz2[3].x,pz2[3].y)));
    lhz = fmaxf(fmaxf(pz2[0].x,pz2[0].y), fmaxf(pz2[1].x,pz2[1].y));
    lhz = fmaxf(lhz, fmaxf(fmaxf(pz2[2].x,pz2[2].y), fmaxf(pz2[3].x,pz2[3].y)));
  }
  __syncthreads();
  int far = 0;
  bool isf32 = (*flag != 0);
  float* outf = (float*)d_out; unsigned short* outh = (unsigned short*)d_out;
  int ln = tid & 63, w = tid >> 6;
  unsigned cached_lo = 0u, cached_hi = 0u;
  float lmax = 1e10f;                      // lane's max dmin over its 8 points
  int rot = 0;
  for (int s = 0; s < SS; s++){
    int rotn = rot + 1; if (rotn == 3) rotn = 0;
    float4 cf = *(const float4*)&sxyz4[(size_t)far*4];
    float cx = cf.x, cy = cf.y, cz = cf.z;
    if (tid == 0){
      fps_idx[b*SS + s] = far;
      size_t o = ((size_t)b*SS + s)*3;
      if (isf32){ outf[o]=cx; outf[o+1]=cy; outf[o+2]=cz; }
      else { outh[o]=f2bf(cx); outh[o+1]=f2bf(cy); outh[o+2]=f2bf(cz); }
    }
    if (tid == 64){ rk[rotn][0] = 0ull; rk[rotn][1] = 0ull; }  // slot quiescent since s-2
    float dxl = fmaxf(fmaxf(llx - cx, cx - lhx), 0.f);
    float dyl = fmaxf(fmaxf(lly - cy, cy - lhy), 0.f);
    float dzl = fmaxf(fmaxf(llz - cz, cz - lhz), 0.f);
    float d2l = (dxl*dxl + dyl*dyl + dzl*dzl) * 0.99999f;
    bool upd = (s == 0) || __any(d2l < lmax);
    if (upd){
      f32x2_t cx2 = (f32x2_t){cx, cx}, cy2 = (f32x2_t){cy, cy}, cz2 = (f32x2_t){cz, cz};
      bool ch = false;
      {
        #pragma clang fp contract(off)
        #pragma unroll
        for (int q = 0; q < 4; q++){
          f32x2_t dx = px2[q] - cx2, dy = py2[q] - cy2, dz = pz2[q] - cz2;
          f32x2_t t = dx*dx;
          t = t + dy*dy;
          t = t + dz*dz;
          ch = ch | (t.x < dmin2[q].x) | (t.y < dmin2[q].y);
          dmin2[q].x = fminf(dmin2[q].x, t.x);
          dmin2[q].y = fminf(dmin2[q].y, t.y);
        }
      }
      if (__any(ch)){
        float m0 = fmaxf(fmaxf(dmin2[0].x, dmin2[0].y), fmaxf(dmin2[1].x, dmin2[1].y));
        float m1 = fmaxf(fmaxf(dmin2[2].x, dmin2[2].y), fmaxf(dmin2[3].x, dmin2[3].y));
        float lm = fmaxf(m0, m1);
        lmax = lm;                         // refresh lane bound (free byproduct)
        lm = dpp_maxf<0x111>(lm); lm = dpp_maxf<0x112>(lm);
        lm = dpp_maxf<0x114>(lm); lm = dpp_maxf<0x118>(lm);
        lm = dpp_maxf<0x142>(lm); lm = dpp_maxf<0x143>(lm);
        float wmax = i2f(__builtin_amdgcn_readlane(f2i(lm), 63));
        unsigned cand = 0xFFFFFFFFu;
        #pragma unroll
        for (int q = 0; q < 4; q++){
          if (dmin2[q].x == wmax){ unsigned u = (unsigned)io[2*q];   cand = u < cand ? u : cand; }
          if (dmin2[q].y == wmax){ unsigned u = (unsigned)io[2*q+1]; cand = u < cand ? u : cand; }
        }
        cand = dpp_minu<0x111>(cand); cand = dpp_minu<0x112>(cand);
        cand = dpp_minu<0x114>(cand); cand = dpp_minu<0x118>(cand);
        cand = dpp_minu<0x142>(cand); cand = dpp_minu<0x143>(cand);
        unsigned cmin = (unsigned)__builtin_amdgcn_readlane((int)cand, 63);
        cached_hi = (unsigned)f2i(wmax);
        cached_lo = ~cmin;
      }
    }
    if (ln == 63)
      atomicMax(&rk[rot][w >> 3], (((unsigned long long)cached_hi) << 32) | cached_lo);
    __syncthreads();
    unsigned long long k0 = rk[rot][0], k1 = rk[rot][1];
    unsigned long long kk = (k1 > k0) ? k1 : k0;
    far = (int)(~(unsigned)kk);
    rot = rotn;
  }
}

// ---------------- kNN: radix-histogram selection, coalesced planar loads ----------------
__global__ __launch_bounds__(256) void knn_kernel(
    const float* psx, const float* psy, const float* psz, const int* ior,
    const float* xyzf, const int* fps_idx, int* knn){
  int cg = blockIdx.x;
  int b = cg >> 11;
  int tid = threadIdx.x;
  const float* xb = xyzf + (size_t)b*NN*3;
  __shared__ unsigned hist[4096];
  __shared__ unsigned long long cand[512];
  __shared__ unsigned psum[256];
  __shared__ unsigned exbase[64];
  __shared__ float scc[3];
  __shared__ int sB, sBase, sCl, sCc;
  __shared__ unsigned long long rmin[4];
  __shared__ unsigned long long swin;

  if (tid == 0){
    int f = fps_idx[cg];
    scc[0] = xb[f*3]; scc[1] = xb[f*3+1]; scc[2] = xb[f*3+2];
    sCl = 0; sCc = 0;
  }
  #pragma unroll
  for (int i = 0; i < 16; i++) hist[tid*16 + i] = 0;
  __syncthreads();
  float cx = scc[0], cy = scc[1], cz = scc[2];

  float dv[32]; int iv[32];
  const float4* qx = (const float4*)(psx + b*NN);
  const float4* qy = (const float4*)(psy + b*NN);
  const float4* qz = (const float4*)(psz + b*NN);
  const int4*   qi = (const int4*)(ior + b*NN);
  {
    #pragma clang fp contract(off)
    #pragma unroll
    for (int k = 0; k < 8; k++){
      float4 X = qx[k*256 + tid];
      float4 Y = qy[k*256 + tid];
      float4 Z = qz[k*256 + tid];
      int4   I = qi[k*256 + tid];
      float xs_[4] = {X.x, X.y, X.z, X.w};
      float ys_[4] = {Y.x, Y.y, Y.z, Y.w};
      float zs_[4] = {Z.x, Z.y, Z.z, Z.w};
      int   is_[4] = {I.x, I.y, I.z, I.w};
      #pragma unroll
      for (int r = 0; r < 4; r++){
        float dx = cx - xs_[r], dy = cy - ys_[r], dz = cz - zs_[r];
        dv[k*4 + r] = dx*dx + dy*dy + dz*dz;
        iv[k*4 + r] = is_[r];
      }
    }
  }
  #pragma unroll
  for (int t = 0; t < 32; t++)
    atomicAdd(&hist[((unsigned)f2i(dv[t])) >> 20], 1u);
  __syncthreads();
  unsigned lsum = 0;
  #pragma unroll
  for (int i = 0; i < 16; i++) lsum += hist[tid*16 + i];
  psum[tid] = lsum;
  __syncthreads();
  if (tid < 64){
    unsigned s4 = psum[tid*4] + psum[tid*4+1] + psum[tid*4+2] + psum[tid*4+3];
    unsigned inc = s4;
    #pragma unroll
    for (int off = 1; off < 64; off <<= 1){
      unsigned o = __shfl_up(inc, off);
      if (tid >= off) inc += o;
    }
    exbase[tid] = inc - s4;
  }
  __syncthreads();
  {
    int g4 = tid >> 2;
    unsigned ex = exbase[g4];
    for (int j = g4*4; j < tid; j++) ex += psum[j];
    unsigned run = ex;
    #pragma unroll
    for (int i = 0; i < 16; i++){
      unsigned c = hist[tid*16 + i];
      if (run < 32u && run + c >= 32u){ sB = tid*16 + i; sBase = (int)run; }
      run += c;
    }
  }
  __syncthreads();
  int Bbin = sB, base = sBase;
  int out = cg << 5;
  #pragma unroll
  for (int t = 0; t < 32; t++){
    unsigned bits = (unsigned)f2i(dv[t]);
    unsigned hb = bits >> 20;
    int idx = iv[t];
    if ((int)hb < Bbin){
      int sl = atomicAdd(&sCl, 1);
      knn[out + sl] = idx;
    } else if ((int)hb == Bbin){
      int c = atomicAdd(&sCc, 1);
      if (c < 512) cand[c] = (((unsigned long long)bits) << 32) | (unsigned)idx;
    }
  }
  __syncthreads();
  int cc = sCc; if (cc > 512) cc = 512;
  int r = 32 - base;
  for (int round = 0; round < r; round++){
    unsigned long long lm = ~0ull;
    for (int i = tid; i < cc; i += 256){
      unsigned long long v = cand[i];
      if (v < lm) lm = v;
    }
    #pragma unroll
    for (int off = 1; off < 64; off <<= 1){
      unsigned long long o = __shfl_xor(lm, off);
      if (o < lm) lm = o;
    }
    if ((tid & 63) == 0) rmin[tid >> 6] = lm;
    __syncthreads();
    if (tid == 0){
      unsigned long long m = rmin[0];
      #pragma unroll
      for (int q = 1; q < 4; q++) if (rmin[q] < m) m = rmin[q];
      swin = m;
      knn[out + base + round] = (int)(unsigned)m;
    }
    __syncthreads();
    unsigned long long m = swin;
    for (int i = tid; i < cc; i += 256)
      if (cand[i] == m) cand[i] = ~0ull;
    __syncthreads();
  }
}

// ---------------- materialized MLP passes (BN finalize folded in) ----------------
__device__ __forceinline__ bf16x8_t bfrag(const unsigned short* wp, int f, int lane){
  return *(const bf16x8_t*)(wp + ((size_t)f << 9) + (lane << 3));
}
__device__ __forceinline__ bf16x8_t bn_frag(bf16x8_t v, const float* a, const float* c, int kbase){
  float4 a0 = *(const float4*)(a + kbase); float4 a1 = *(const float4*)(a + kbase + 4);
  float4 c0 = *(const float4*)(c + kbase); float4 c1 = *(const float4*)(c + kbase + 4);
  float av[8] = {a0.x,a0.y,a0.z,a0.w,a1.x,a1.y,a1.z,a1.w};
  float cv[8] = {c0.x,c0.y,c0.z,c0.w,c1.x,c1.y,c1.z,c1.w};
  bf16x8_t r;
  #pragma unroll
  for (int j = 0; j < 8; j++)
    r[j] = (short)f2bf(fmaxf(bf2f((unsigned short)v[j])*av[j] + cv[j], 0.f));
  return r;
}

template<int TILES>
__global__ __launch_bounds__(256) void passA(
    const float* __restrict__ xyzf, const unsigned short* __restrict__ ptsb,
    const int* __restrict__ fpsi, const int* __restrict__ knn,
    const unsigned short* __restrict__ w0p,
    unsigned short* __restrict__ y0g, float* osum, float* osq)
{
  __shared__ unsigned short xb0[64*104];
  __shared__ unsigned short st[64*72];
  __shared__ float sacc[128];
  int tid = threadIdx.x, lane = tid & 63, w = tid >> 6;
  int l15 = lane & 15, quad = lane >> 4;
  float ssum[4], ssq[4];
  #pragma unroll
  for (int c = 0; c < 4; c++){ ssum[c] = 0.f; ssq[c] = 0.f; }
  if (tid < 128) sacc[tid] = 0.f;
  __syncthreads();

  for (int t = 0; t < TILES; t++){
    int row0 = (blockIdx.x * TILES + t) * 64;
    {
      int r = tid >> 2, p = tid & 3;
      int g = row0 + r;
      int bq = g >> 16, s = (g >> 5) & 2047;
      int n = knn[g];
      const bf16x8_t* pr = (const bf16x8_t*)(ptsb + (((size_t)bq*NN + n) << 6));
      *(bf16x8_t*)&xb0[r*104 + p*16]     = pr[p*2];
      *(bf16x8_t*)&xb0[r*104 + p*16 + 8] = pr[p*2 + 1];
      if (p == 3){
        const float* xbp = xyzf + (size_t)bq*NN*3;
        int f = fpsi[(bq << 11) + s];
        float dx = xbp[n*3]   - xbp[f*3];
        float dy = xbp[n*3+1] - xbp[f*3+1];
        float dz = xbp[n*3+2] - xbp[f*3+2];
        bf16x8_t v = {(short)f2bf(dx), (short)f2bf(dy), (short)f2bf(dz), 0,0,0,0,0};
        bf16x8_t z = {0,0,0,0,0,0,0,0};
        *(bf16x8_t*)&xb0[r*104 + 64] = v;
        *(bf16x8_t*)&xb0[r*104 + 72] = z;
        *(bf16x8_t*)&xb0[r*104 + 80] = z;
        *(bf16x8_t*)&xb0[r*104 + 88] = z;
      }
    }
    bf16x8_t a0[3];
    #pragma unroll
    for (int ks = 0; ks < 3; ks++)
      a0[ks] = *(const bf16x8_t*)&xb0[(w*16 + l15)*104 + ks*32 + quad*8];
    #pragma unroll
    for (int ct = 0; ct < 4; ct++){
      f32x4_t a = {0.f,0.f,0.f,0.f};
      #pragma unroll
      for (int ks = 0; ks < 3; ks++)
        a = __builtin_amdgcn_mfma_f32_16x16x32_bf16(a0[ks], bfrag(w0p, ct*3+ks, lane), a, 0, 0, 0);
      #pragma unroll
      for (int r = 0; r < 4; r++){
        float v = a[r]; ssum[ct] += v; ssq[ct] += v*v;
        st[(w*16 + quad*4 + r)*72 + ct*16 + l15] = f2bf(v);
      }
    }
    __syncthreads();
    #pragma unroll
    for (int p = 0; p < 2; p++){
      int idx = p*2048 + tid*8; int r = idx >> 6; int c = idx & 63;
      *(bf16x8_t*)(y0g + (size_t)row0*64 + idx) = *(const bf16x8_t*)&st[r*72 + c];
    }
    __syncthreads();
  }
  #pragma unroll
  for (int c = 0; c < 4; c++){
    ssum[c] += __shfl_xor(ssum[c], 16); ssum[c] += __shfl_xor(ssum[c], 32);
    ssq [c] += __shfl_xor(ssq [c], 16); ssq [c] += __shfl_xor(ssq [c], 32);
  }
  if (quad == 0){
    #pragma unroll
    for (int c = 0; c < 4; c++){
      atomicAdd(&sacc[c*16 + l15], ssum[c]);
      atomicAdd(&sacc[64 + c*16 + l15], ssq[c]);
    }
  }
  __syncthreads();
  if (tid < 64){
    atomicAdd(&osum[tid], sacc[tid]);
    atomicAdd(&osq [tid], sacc[64 + tid]);
  }
}

template<int TILES>
__global__ __launch_bounds__(256) void passB(
    const unsigned short* __restrict__ y0g, const unsigned short* __restrict__ w1p,
    const float* __restrict__ stats, const float* __restrict__ gbf,
    unsigned short* __restrict__ y1g, float* osum, float* osq)
{
  __shared__ unsigned short st[64*136];
  __shared__ float sacc[256];
  __shared__ __align__(16) float sbn[128];
  int tid = threadIdx.x, lane = tid & 63, w = tid >> 6;
  int l15 = lane & 15, quad = lane >> 4;
  float ssum[8], ssq[8];
  #pragma unroll
  for (int c = 0; c < 8; c++){ ssum[c] = 0.f; ssq[c] = 0.f; }
  sacc[tid] = 0.f;
  if (tid < 64){
    const float invM = 1.0f/262144.0f;
    float mu = stats[tid]*invM;
    float var = fmaxf(stats[64+tid]*invM - mu*mu, 0.f);
    float inv = 1.0f/sqrtf(var + 1e-5f);
    float av = gbf[tid]*inv;
    sbn[tid] = av; sbn[64+tid] = gbf[64+tid] - mu*av;
  }
  __syncthreads();

  for (int t = 0; t < TILES; t++){
    int row0 = (blockIdx.x * TILES + t) * 64;
    int row = row0 + w*16 + l15;
    bf16x8_t a1[2];
    #pragma unroll
    for (int ks = 0; ks < 2; ks++){
      bf16x8_t v = *(const bf16x8_t*)(y0g + (size_t)row*64 + ks*32 + quad*8);
      a1[ks] = bn_frag(v, sbn, sbn + 64, ks*32 + quad*8);
    }
    #pragma unroll
    for (int ct = 0; ct < 8; ct++){
      f32x4_t a = {0.f,0.f,0.f,0.f};
      #pragma unroll
      for (int ks = 0; ks < 2; ks++)
        a = __builtin_amdgcn_mfma_f32_16x16x32_bf16(a1[ks], bfrag(w1p, ct*2+ks, lane), a, 0, 0, 0);
      #pragma unroll
      for (int r = 0; r < 4; r++){
        float v = a[r]; ssum[ct] += v; ssq[ct] += v*v;
        st[(w*16 + quad*4 + r)*136 + ct*16 + l15] = f2bf(v);
      }
    }
    __syncthreads();
    #pragma unroll
    for (int p = 0; p < 4; p++){
      int idx = p*2048 + tid*8; int r = idx >> 7; int c = idx & 127;
      *(bf16x8_t*)(y1g + (size_t)row0*128 + idx) = *(const bf16x8_t*)&st[r*136 + c];
    }
    __syncthreads();
  }
  #pragma unroll
  for (int c = 0; c < 8; c++){
    ssum[c] += __shfl_xor(ssum[c], 16); ssum[c] += __shfl_xor(ssum[c], 32);
    ssq [c] += __shfl_xor(ssq [c], 16); ssq [c] += __shfl_xor(ssq [c], 32);
  }
  if (quad == 0){
    #pragma unroll
    for (int c = 0; c < 8; c++){
      atomicAdd(&sacc[c*16 + l15], ssum[c]);
      atomicAdd(&sacc[128 + c*16 + l15], ssq[c]);
    }
  }
  __syncthreads();
  if (tid < 128){
    atomicAdd(&osum[tid], sacc[tid]);
    atomicAdd(&osq [tid], sacc[128 + tid]);
  }
}

template<int TILES>
__global__ __launch_bounds__(256) void passC(
    const unsigned short* __restrict__ y1g, const unsigned short* __restrict__ w2p,
    const float* __restrict__ stats, const float* __restrict__ gbf,
    float* osum, float* osq)
{
  __shared__ float sacc[512];
  __shared__ __align__(16) float sbn[256];
  int tid = threadIdx.x, lane = tid & 63, w = tid >> 6;
  int l15 = lane & 15, quad = lane >> 4;
  float ssum[16], ssq[16];
  #pragma unroll
  for (int c = 0; c < 16; c++){ ssum[c] = 0.f; ssq[c] = 0.f; }
  sacc[tid] = 0.f; sacc[tid + 256] = 0.f;
  if (tid < 128){
    const float invM = 1.0f/262144.0f;
    float mu = stats[128+tid]*invM;
    float var = fmaxf(stats[256+tid]*invM - mu*mu, 0.f);
    float inv = 1.0f/sqrtf(var + 1e-5f);
    float av = gbf[128+tid]*inv;
    sbn[tid] = av; sbn[128+tid] = gbf[256+tid] - mu*av;
  }
  __syncthreads();

  for (int t = 0; t < TILES; t++){
    int row0 = (blockIdx.x * TILES + t) * 64;
    int row = row0 + w*16 + l15;
    bf16x8_t a2[4];
    #pragma unroll
    for (int ks = 0; ks < 4; ks++){
      bf16x8_t v = *(const bf16x8_t*)(y1g + (size_t)row*128 + ks*32 + quad*8);
      a2[ks] = bn_frag(v, sbn, sbn + 128, ks*32 + quad*8);
    }
    #pragma unroll
    for (int ct = 0; ct < 16; ct++){
      f32x4_t a = {0.f,0.f,0.f,0.f};
      #pragma unroll
      for (int ks = 0; ks < 4; ks++)
        a = __builtin_amdgcn_mfma_f32_16x16x32_bf16(a2[ks], bfrag(w2p, ct*4+ks, lane), a, 0, 0, 0);
      #pragma unroll
      for (int r = 0; r < 4; r++){ float v = a[r]; ssum[ct] += v; ssq[ct] += v*v; }
    }
  }
  #pragma unroll
  for (int c = 0; c < 16; c++){
    ssum[c] += __shfl_xor(ssum[c], 16); ssum[c] += __shfl_xor(ssum[c], 32);
    ssq [c] += __shfl_xor(ssq [c], 16); ssq [c] += __shfl_xor(ssq [c], 32);
  }
  if (quad == 0){
    #pragma unroll
    for (int c = 0; c < 16; c++){
      atomicAdd(&sacc[c*16 + l15], ssum[c]);
      atomicAdd(&sacc[256 + c*16 + l15], ssq[c]);
    }
  }
  __syncthreads();
  if (tid < 256){
    atomicAdd(&osum[tid], sacc[tid]);
    atomicAdd(&osq [tid], sacc[256 + tid]);
  }
}

__global__ __launch_bounds__(256) void passD(
    const unsigned short* __restrict__ y1g, const unsigned short* __restrict__ w2p,
    const float* __restrict__ stats, const float* __restrict__ gbf,
    void* d_out, const int* __restrict__ flag)
{
  __shared__ float smax[1024];
  __shared__ __align__(16) float sbn[768];  // a1[128] c1[128] a2[256] c2[256]
  int tid = threadIdx.x, lane = tid & 63, w = tid >> 6;
  int l15 = lane & 15, quad = lane >> 4;
  {
    const float invM = 1.0f/262144.0f;
    if (tid < 128){
      float mu = stats[128+tid]*invM;
      float var = fmaxf(stats[256+tid]*invM - mu*mu, 0.f);
      float inv = 1.0f/sqrtf(var + 1e-5f);
      float av = gbf[128+tid]*inv;
      sbn[tid] = av; sbn[128+tid] = gbf[256+tid] - mu*av;
    }
    float mu2 = stats[384+tid]*invM;
    float var2 = fmaxf(stats[640+tid]*invM - mu2*mu2, 0.f);
    float inv2 = 1.0f/sqrtf(var2 + 1e-5f);
    float av2 = gbf[384+tid]*inv2;
    sbn[256+tid] = av2; sbn[512+tid] = gbf[640+tid] - mu2*av2;
  }
  __syncthreads();
  int row0 = blockIdx.x * 64;
  int row = row0 + w*16 + l15;
  bf16x8_t a2[4];
  #pragma unroll
  for (int ks = 0; ks < 4; ks++){
    bf16x8_t v = *(const bf16x8_t*)(y1g + (size_t)row*128 + ks*32 + quad*8);
    a2[ks] = bn_frag(v, sbn, sbn + 128, ks*32 + quad*8);
  }
  #pragma unroll
  for (int ct = 0; ct < 16; ct++){
    f32x4_t a = {0.f,0.f,0.f,0.f};
    #pragma unroll
    for (int ks = 0; ks < 4; ks++)
      a = __builtin_amdgcn_mfma_f32_16x16x32_bf16(a2[ks], bfrag(w2p, ct*4+ks, lane), a, 0, 0, 0);
    int o = ct*16 + l15;
    float ga = sbn[256 + o], gc = sbn[512 + o];
    float m = fmaxf(fmaxf(a[0]*ga + gc, a[1]*ga + gc), fmaxf(a[2]*ga + gc, a[3]*ga + gc));
    m = fmaxf(m, __shfl_xor(m, 16));
    m = fmaxf(m, __shfl_xor(m, 32));
    if (quad == 0) smax[w*256 + o] = m;
  }
  __syncthreads();
  float v0 = fmaxf(fmaxf(smax[tid], smax[256 + tid]), 0.f);
  float v1 = fmaxf(fmaxf(smax[512 + tid], smax[768 + tid]), 0.f);
  int cg = blockIdx.x * 2;
  bool isf32 = (*flag != 0);
  int b0 = cg >> 11, s0 = cg & 2047;
  int b1 = (cg+1) >> 11, s1 = (cg+1) & 2047;
  size_t o0 = (size_t)BB*SS*3 + (((size_t)(b0*256 + tid)) << 11) + s0;
  size_t o1 = (size_t)BB*SS*3 + (((size_t)(b1*256 + tid)) << 11) + s1;
  if (isf32){ ((float*)d_out)[o0] = v0; ((float*)d_out)[o1] = v1; }
  else { ((unsigned short*)d_out)[o0] = f2bf(v0); ((unsigned short*)d_out)[o1] = f2bf(v1); }
}

// ---------------- workspace layout (bytes) ----------------
#define OFF_FLAG   0u
#define OFF_FPS    256u
#define OFF_KNN    33024u
#define OFF_STATS  1081600u
#define OFF_XYZF   1088768u
#define OFF_GB     1481984u
#define OFF_W0P    1485568u
#define OFF_W1P    1497856u
#define OFF_W2P    1514240u
#define OFF_PTSB   1579776u
#define OFF_Y0     5774336u
#define OFF_Y1     39328768u
#define OFF_PSX    (OFF_Y1)
#define OFF_PSY    (OFF_Y1 + 131072u)
#define OFF_PSZ    (OFF_Y1 + 262144u)
#define OFF_IOR    (OFF_Y1 + 393216u)

extern "C" void kernel_launch(void* const* d_in, const int* in_sizes, int n_in,
                              void* d_out, int out_size, void* d_ws, size_t ws_size,
                              hipStream_t stream){
  char* ws = (char*)d_ws;
  int*   flag  = (int*)(ws + OFF_FLAG);
  int*   fpsi  = (int*)(ws + OFF_FPS);
  int*   knn   = (int*)(ws + OFF_KNN);
  float* stats = (float*)(ws + OFF_STATS);
  float* xyzf  = (float*)(ws + OFF_XYZF);
  float* gbf   = (float*)(ws + OFF_GB);
  unsigned short* w0p = (unsigned short*)(ws + OFF_W0P);
  unsigned short* w1p = (unsigned short*)(ws + OFF_W1P);
  unsigned short* w2p = (unsigned short*)(ws + OFF_W2P);
  unsigned short* ptsb = (unsigned short*)(ws + OFF_PTSB);
  unsigned short* y0g = (unsigned short*)(ws + OFF_Y0);
  unsigned short* y1g = (unsigned short*)(ws + OFF_Y1);
  float* psx = (float*)(ws + OFF_PSX);
  float* psy = (float*)(ws + OFF_PSY);
  float* psz = (float*)(ws + OFF_PSZ);
  int*   ior = (int*)(ws + OFF_IOR);

  detect_kernel<<<1, 256, 0, stream>>>(d_in[1], flag);
  prep_morton<<<51, 1024, 0, stream>>>(d_in[0], d_in[2], d_in[5], d_in[8],
                                       d_in[3], d_in[4], d_in[6], d_in[7], d_in[9], d_in[10],
                                       xyzf, psx, psy, psz, ior,
                                       w0p, w1p, w2p, gbf, stats, flag);
  fps_kernel<<<4 + 128, 1024, 0, stream>>>(xyzf, psx, psy, psz, ior, fpsi, d_out, flag,
                                           d_in[1], ptsb);
  knn_kernel<<<BB*SS, 256, 0, stream>>>(psx, psy, psz, ior, xyzf, fpsi, knn);

  passA<4><<<1024, 256, 0, stream>>>(xyzf, ptsb, fpsi, knn, w0p, y0g, stats + 0, stats + 64);
  passB<4><<<1024, 256, 0, stream>>>(y0g, w1p, stats, gbf, y1g, stats + 128, stats + 256);
  passC<4><<<1024, 256, 0, stream>>>(y1g, w2p, stats, gbf, stats + 384, stats + 640);
  passD<<<4096, 256, 0, stream>>>(y1g, w2p, stats, gbf, d_out, flag);
  (void)in_sizes; (void)n_in; (void)out_size; (void)ws_size;
}